// Round 5
// baseline (1452.145 us; speedup 1.0000x reference)
//
#include <hip/hip_runtime.h>
#include <hip/hip_bf16.h>
#include <math.h>

#define NN 50000
#define NE 800000
#define NG 256
#define H 128
#define NIN 64
#define EIN 16
#define NL 3
#define LEPS 1e-5f

typedef short bf16x8 __attribute__((ext_vector_type(8)));
typedef float f32x4 __attribute__((ext_vector_type(4)));
typedef float f32x16 __attribute__((ext_vector_type(16)));
typedef unsigned u32x4 __attribute__((ext_vector_type(4)));

__device__ __forceinline__ short bf16rne(float x) {
  unsigned u = __float_as_uint(x);
  unsigned r = u + 0x7fff + ((u >> 16) & 1);
  return (short)(r >> 16);
}

// pack two floats to bf16 pair (lo in low short) — RNE, same bits as bf16rne
__device__ __forceinline__ unsigned pk2(float lo, float hi) {
  __hip_bfloat162 h = __float22bfloat162_rn(make_float2(lo, hi));
  return *(unsigned*)&h;
}

__device__ __forceinline__ float wsum(float v) {
#pragma unroll
  for (int m = 1; m < 64; m <<= 1) v += __shfl_xor(v, m, 64);
  return v;
}

__device__ __forceinline__ float lds_f32(const short* p) {
  short2 s = *(const short2*)p;
  return __uint_as_float((unsigned)(unsigned short)s.x |
                         ((unsigned)(unsigned short)s.y << 16));
}

// ---------------- sort-by-dst pipeline (once per launch) ----------------
__global__ __launch_bounds__(256) void k_count(const int* __restrict__ eidx,
                                               unsigned* __restrict__ cnt) {
  int t = blockIdx.x * 256 + threadIdx.x;
  if (t < NE) atomicAdd(&cnt[eidx[NE + t]], 1u);
}

__global__ __launch_bounds__(1024) void k_scan(const unsigned* __restrict__ cnt,
                                               unsigned* __restrict__ rowptr) {
  __shared__ unsigned part[16];
  __shared__ unsigned carry_s;
  const int tid = threadIdx.x, lane = tid & 63, wid = tid >> 6;
  if (tid == 0) carry_s = 0;
  __syncthreads();
  for (int base = 0; base < NN; base += 1024) {
    int i = base + tid;
    unsigned v = (i < NN) ? cnt[i] : 0u;
    unsigned incl = v;
#pragma unroll
    for (int off = 1; off < 64; off <<= 1) {
      unsigned t = __shfl_up(incl, off, 64);
      if (lane >= off) incl += t;
    }
    if (lane == 63) part[wid] = incl;
    __syncthreads();
    if (tid == 0) {
      unsigned s = 0;
#pragma unroll
      for (int w = 0; w < 16; w++) { unsigned t = part[w]; part[w] = s; s += t; }
    }
    __syncthreads();
    unsigned carry = carry_s;
    if (i < NN) rowptr[i] = carry + part[wid] + incl - v;
    __syncthreads();
    if (tid == 1023) carry_s = carry + part[15] + incl;
    __syncthreads();
  }
}

// ---------------- K_fold: LN-fold precompute (once) --------------------------
// W2e_ext[l]: 32 k-rows x 256 n, bf16, B-frag layout:
//   f = nt*2 + ks2 (f<16): elem ((l*16+f)*64+lane)*8+j = W[k][n],
//   k = ks2*16 + (lane>>5)*8 + j, n = nt*32 + (lane&31).
//   k<16 : We·diag(g)·Wbot ;  k=16: (be∘g)@Wbot ; k=17: g@Wbot ;
//   k=18 : b_ln@Wbot + out-bias (gate_b | msg_b1) ; k>18: 0.
// Pairs with per-edge A-frags [rs·ea] (k 0..15) and [rs, −rs·μ, 1, 0..]
// (k 16..31) so LN corrections + biases ride the MFMA (verified in R4 run).
// stats: M[16][16]=We·We^T, wcs[16]=rowsum(We), v[16]=We@be, cc=Σbe², sbe=Σbe
__global__ __launch_bounds__(256) void k_fold(
    const float* __restrict__ gate_w, const float* __restrict__ msg_w1,
    const float* __restrict__ gate_b, const float* __restrict__ msg_b1,
    const float* __restrict__ e_enc_w, const float* __restrict__ e_enc_b,
    const float* __restrict__ e_ln_g, const float* __restrict__ e_ln_b,
    short* __restrict__ w2e, float* __restrict__ stats) {
  const int S_W2E = 3 * 8192;
  const int S_ST = S_W2E + 290;
  int tid = blockIdx.x * 256 + threadIdx.x;
  if (tid >= S_ST) return;
  if (tid < S_W2E) {
    int l = tid / 8192, e = tid % 8192;
    int f = e >> 9, lane = (e >> 3) & 63, j = e & 7;
    int nt = f >> 1, ks2 = f & 1;
    int k = ks2 * 16 + (lane >> 5) * 8 + j;
    int n = nt * 32 + (lane & 31);
    float s = 0.f;
    if (k < 19) {
      for (int m = 0; m < 128; m++) {
        float w = (n < 128) ? gate_w[((size_t)l * 256 + 128 + m) * 128 + n]
                            : msg_w1[((size_t)l * 256 + 128 + m) * 128 + (n - 128)];
        float fm = (k < 16)   ? e_enc_w[k * 128 + m] * e_ln_g[m]
                 : (k == 16)  ? e_enc_b[m] * e_ln_g[m]
                 : (k == 17)  ? e_ln_g[m]
                              : e_ln_b[m];
        s += fm * w;
      }
      if (k == 18)
        s += (n < 128) ? gate_b[l * 128 + n] : msg_b1[l * 128 + (n - 128)];
    }
    w2e[tid] = bf16rne(s);
  } else {
    int e = tid - S_W2E;
    if (e < 256) {
      int i = e >> 4, j = e & 15;
      float s = 0.f;
      for (int n = 0; n < 128; n++)
        s += e_enc_w[i * 128 + n] * e_enc_w[j * 128 + n];
      stats[e] = s;
    } else if (e < 272) {
      int k = e - 256;
      float s = 0.f;
      for (int n = 0; n < 128; n++) s += e_enc_w[k * 128 + n];
      stats[e] = s;
    } else if (e < 288) {
      int k = e - 272;
      float s = 0.f;
      for (int n = 0; n < 128; n++) s += e_enc_w[k * 128 + n] * e_enc_b[n];
      stats[e] = s;
    } else if (e == 288) {
      float s = 0.f;
      for (int n = 0; n < 128; n++) s += e_enc_b[n] * e_enc_b[n];
      stats[e] = s;
    } else {
      float s = 0.f;
      for (int n = 0; n < 128; n++) s += e_enc_b[n];
      stats[e] = s;
    }
  }
}

// ---------------- k_scatter: sort edges + bf16 ea + per-edge LN stats --------
// (exact R3 version — 1023 µs run)
__global__ __launch_bounds__(256) void k_scatter(
    const int* __restrict__ eidx, const float* __restrict__ ea,
    const unsigned* __restrict__ rowptr, unsigned* __restrict__ cursor,
    const float* __restrict__ stats,
    int* __restrict__ src_s, int* __restrict__ dst_s,
    short* __restrict__ ea_bf, float2* __restrict__ rsmu) {
  __shared__ float S[290];
  for (int i = threadIdx.x; i < 290; i += 256) S[i] = stats[i];
  __syncthreads();
  int t = blockIdx.x * 256 + threadIdx.x;
  int s = eidx[t], d = eidx[NE + t];
  unsigned pos = rowptr[d] + atomicAdd(&cursor[d], 1u);
  src_s[pos] = s;
  dst_s[pos] = d;
  const float4* er = (const float4*)(ea + (size_t)t * EIN);
  float4 q0 = er[0], q1 = er[1], q2 = er[2], q3 = er[3];
  float e16[16];
  e16[0]=q0.x; e16[1]=q0.y; e16[2]=q0.z; e16[3]=q0.w;
  e16[4]=q1.x; e16[5]=q1.y; e16[6]=q1.z; e16[7]=q1.w;
  e16[8]=q2.x; e16[9]=q2.y; e16[10]=q2.z; e16[11]=q2.w;
  e16[12]=q3.x; e16[13]=q3.y; e16[14]=q3.z; e16[15]=q3.w;
  short tmp[16];
#pragma unroll
  for (int j = 0; j < 16; j++) tmp[j] = bf16rne(e16[j]);
  short* dstp = ea_bf + (size_t)pos * EIN;
  *(bf16x8*)dstp = *(bf16x8*)tmp;
  *(bf16x8*)(dstp + 8) = *(bf16x8*)(tmp + 8);
  // LN stats (exact fp32)
  float s1 = S[289], s2 = S[288];
#pragma unroll
  for (int k = 0; k < 16; k++) {
    s1 = fmaf(e16[k], S[256 + k], s1);
    s2 = fmaf(2.f * e16[k], S[272 + k], s2);
  }
#pragma unroll
  for (int i = 0; i < 16; i++) {
    float mi = 0.f;
#pragma unroll
    for (int j = 0; j < 16; j++) mi = fmaf(S[i * 16 + j], e16[j], mi);
    s2 = fmaf(e16[i], mi, s2);
  }
  float mu = s1 * (1.f / 128.f);
  float var = s2 * (1.f / 128.f) - mu * mu;
  float rs = rsqrtf(var + LEPS);
  rsmu[pos] = make_float2(rs, mu);
}

// ---------------- K0: pre-swizzle weights (R3 version, benc dropped) ---------
__global__ __launch_bounds__(256) void k_convert_w(
    const float* __restrict__ gate_w, const float* __restrict__ msg_w1,
    const float* __restrict__ msg_w2, const float* __restrict__ res_w1,
    const float* __restrict__ res_w2,
    short* __restrict__ bgh, short* __restrict__ bm2,
    short* __restrict__ brs1, short* __restrict__ brs2) {
  const int S_BGH = 3 * 65536;
  const int S_BM2 = S_BGH + 3 * 16384;
  const int S_BR1 = S_BM2 + 3 * 32768;
  const int S_BR2 = S_BR1 + 3 * 16384;
  int tid = blockIdx.x * 256 + threadIdx.x;
  if (tid >= S_BR2) return;
  if (tid < S_BGH) {
    int l = tid / 65536, e = tid % 65536;
    int f = e >> 9, lane = (e >> 3) & 63, j = e & 7;
    int nt = f >> 4, ks = f & 15;
    int k = ks * 16 + (lane >> 5) * 8 + j;
    int n = nt * 32 + (lane & 31);
    float v = (n < 128) ? gate_w[((size_t)l * 256 + k) * 128 + n]
                        : msg_w1[((size_t)l * 256 + k) * 128 + (n - 128)];
    bgh[tid] = bf16rne(v);
  } else if (tid < S_BM2) {
    int e0 = tid - S_BGH;
    int l = e0 / 16384, e = e0 % 16384;
    int f = e >> 9, lane = (e >> 3) & 63, j = e & 7;
    int nt = f >> 3, ks = f & 7;
    int k = ks * 16 + (lane >> 5) * 8 + j;
    int n = nt * 32 + (lane & 31);
    bm2[e0] = bf16rne(msg_w2[((size_t)l * 128 + k) * 128 + n]);
  } else if (tid < S_BR1) {
    int e0 = tid - S_BM2;
    int l = e0 / 32768, e = e0 % 32768;
    int f = e >> 9, lane = (e >> 3) & 63, j = e & 7;
    int nt = f >> 3, ks = f & 7;
    int k = ks * 32 + (lane >> 4) * 8 + j;
    int n = nt * 16 + (lane & 15);
    brs1[e0] = bf16rne(res_w1[((size_t)l * 256 + k) * 128 + n]);
  } else {
    int e0 = tid - S_BR1;
    int l = e0 / 16384, e = e0 % 16384;
    int f = e >> 9, lane = (e >> 3) & 63, j = e & 7;
    int nt = f >> 2, ks = f & 3;
    int k = ks * 32 + (lane >> 4) * 8 + j;
    int n = nt * 16 + (lane & 15);
    brs2[e0] = bf16rne(res_w2[((size_t)l * 128 + k) * 128 + n]);
  }
}

// ---------------- K1: h = LN(x @ Wn + bn), also emit bf16 copy ----------------
__global__ __launch_bounds__(256) void k_node_encode(
    const float* __restrict__ x, const float* __restrict__ W,
    const float* __restrict__ bias,
    const float* __restrict__ lng, const float* __restrict__ lnb,
    float* __restrict__ h, short* __restrict__ h_bf) {
  __shared__ float xs[4][8 * NIN];
  const int wave = threadIdx.x >> 6, lane = threadIdx.x & 63;
  const int n0 = (blockIdx.x * 4 + wave) * 8;
  float* xt = xs[wave];
  for (int i = lane; i < 8 * NIN; i += 64) {
    int idx = n0 * NIN + i;
    xt[i] = (idx < NN * NIN) ? x[idx] : 0.f;
  }
  __syncthreads();
  const int c0 = lane, c1 = lane + 64;
  float a0[8], a1[8];
#pragma unroll
  for (int j = 0; j < 8; j++) { a0[j] = 0.f; a1[j] = 0.f; }
  for (int k = 0; k < NIN; k++) {
    float w0 = W[k * H + c0], w1 = W[k * H + c1];
#pragma unroll
    for (int j = 0; j < 8; j++) {
      float xv = xt[j * NIN + k];
      a0[j] = fmaf(xv, w0, a0[j]);
      a1[j] = fmaf(xv, w1, a1[j]);
    }
  }
  const float b0 = bias[c0], b1 = bias[c1];
  const float g0 = lng[c0], g1 = lng[c1], lb0 = lnb[c0], lb1 = lnb[c1];
#pragma unroll
  for (int j = 0; j < 8; j++) {
    float v0 = a0[j] + b0, v1 = a1[j] + b1;
    float mean = wsum(v0 + v1) * (1.f / H);
    float d0 = v0 - mean, d1 = v1 - mean;
    float var = wsum(d0 * d0 + d1 * d1) * (1.f / H);
    float rs = rsqrtf(var + LEPS);
    int n = n0 + j;
    if (n < NN) {
      float o0 = d0 * rs * g0 + lb0, o1 = d1 * rs * g1 + lb1;
      h[n * H + c0] = o0;
      h[n * H + c1] = o1;
      h_bf[n * H + c0] = bf16rne(o0);
      h_bf[n * H + c1] = bf16rne(o1);
    }
  }
}

// ---------------- K3: MFMA edge kernel, M=64 edges/wave ----------------------
// Two M=32 A-tiles per wave share every weight fragment (load:MFMA = 1:2),
// halving per-wave weight-load latency exposure and L2 weight traffic (the
// R4 post-mortem diagnosis).  LN corrections + gate/msg1 biases ride W2e's
// extra K-rows (ae2 = [rs, -rs*mu, 1]; verified numerically in R4).  T2 via
// wave-private LDS (R3 structure); fp32 gate; per-t2 gate->msg interleave
// keeps gate live-range at 32 floats.  C/D: col=lane&31,
// row=(reg&3)+8*(reg>>2)+4*(lane>>5).  A/B: m/n=lane&31, k=(lane>>5)*8+j.
__global__ __launch_bounds__(256, 2) void k_edge_mfma(
    const short* __restrict__ ea_bf, const float2* __restrict__ rsmu,
    const int* __restrict__ src_s, const int* __restrict__ dst_s,
    const short* __restrict__ h_bf,
    const short* __restrict__ Bgh, const short* __restrict__ Bm2,
    const short* __restrict__ W2e, const float* __restrict__ mbias2,
    float* __restrict__ agg) {
  __shared__ short regn[4][64 * 136];   // 17.4 KB/wave, 69.6 KB/block
  __shared__ int dsts[4][64];
  const int tid = threadIdx.x;
  const int wave = tid >> 6, lane = tid & 63;
  const int e0 = blockIdx.x * 256 + wave * 64;
  short* R = regn[wave];
  const int c31 = lane & 31, halfl = lane >> 5;
  const int koff = halfl * 8;

  dsts[wave][lane] = dst_s[e0 + lane];

  // ---- A operands for both edge sets ----
  bf16x8 af0[8], af1[8], ae[2], ae2[2];
#pragma unroll
  for (int s = 0; s < 2; s++) {
    const int er = e0 + s * 32 + c31;
    const int srow = src_s[er];
#pragma unroll
    for (int ks = 0; ks < 8; ks++) {
      bf16x8 v = *(const bf16x8*)(h_bf + (size_t)srow * H + ks * 16 + koff);
      if (s == 0) af0[ks] = v; else af1[ks] = v;
    }
    const float2 rm = rsmu[er];
    bf16x8 raw = *(const bf16x8*)(ea_bf + (size_t)er * EIN + koff);
    u32x4 v;
#pragma unroll
    for (int p = 0; p < 4; p++) {
      float lo = __uint_as_float(((unsigned)(unsigned short)raw[2 * p]) << 16) * rm.x;
      float hi = __uint_as_float(((unsigned)(unsigned short)raw[2 * p + 1]) << 16) * rm.x;
      v[p] = pk2(lo, hi);
    }
    ae[s] = __builtin_bit_cast(bf16x8, v);
    u32x4 w;
    w[0] = halfl ? 0u : pk2(rm.x, -rm.x * rm.y);   // k16=rs, k17=-rs*mu
    w[1] = halfl ? 0u : 0x00003F80u;               // k18=1.0
    w[2] = 0u; w[3] = 0u;
    ae2[s] = __builtin_bit_cast(bf16x8, w);
  }

  // ---- hidden tiles (nt 4..7): dual chains -> relu -> T2 rows [0..63] ----
#pragma unroll
  for (int ht = 0; ht < 4; ht++) {
    const int nt = 4 + ht;
    bf16x8 w0 = *(const bf16x8*)(W2e + (size_t)((nt * 2 + 0) * 64 + lane) * 8);
    bf16x8 w1 = *(const bf16x8*)(W2e + (size_t)((nt * 2 + 1) * 64 + lane) * 8);
    f32x16 A0 = __builtin_amdgcn_mfma_f32_32x32x16_bf16(ae[0], w0, (f32x16)(0.f), 0, 0, 0);
    f32x16 A1 = __builtin_amdgcn_mfma_f32_32x32x16_bf16(ae[1], w0, (f32x16)(0.f), 0, 0, 0);
    A0 = __builtin_amdgcn_mfma_f32_32x32x16_bf16(ae2[0], w1, A0, 0, 0, 0);
    A1 = __builtin_amdgcn_mfma_f32_32x32x16_bf16(ae2[1], w1, A1, 0, 0, 0);
#pragma unroll
    for (int ks = 0; ks < 8; ks++) {
      bf16x8 bg = *(const bf16x8*)(Bgh + (size_t)((nt * 16 + ks) * 64 + lane) * 8);
      A0 = __builtin_amdgcn_mfma_f32_32x32x16_bf16(af0[ks], bg, A0, 0, 0, 0);
      A1 = __builtin_amdgcn_mfma_f32_32x32x16_bf16(af1[ks], bg, A1, 0, 0, 0);
    }
    const int col = ht * 32 + c31;
#pragma unroll
    for (int r = 0; r < 16; r++) {
      int row = (r & 3) + 8 * (r >> 2) + 4 * halfl;
      R[row * 136 + col] = bf16rne(fmaxf(A0[r], 0.f));
      R[(32 + row) * 136 + col] = bf16rne(fmaxf(A1[r], 0.f));
    }
  }

  // ---- GEMM2 A-frags from T2 (snapshot before msg staging clobbers) ----
  bf16x8 a2_0[8], a2_1[8];
#pragma unroll
  for (int ks = 0; ks < 8; ks++) {
    a2_0[ks] = *(const bf16x8*)&R[c31 * 136 + ks * 16 + koff];
    a2_1[ks] = *(const bf16x8*)&R[(32 + c31) * 136 + ks * 16 + koff];
  }

  // ---- per half: (gate tile -> msg tile -> stage) x2, then flush ----
#pragma unroll
  for (int halfM = 0; halfM < 2; halfM++) {
#pragma unroll
    for (int t2 = 0; t2 < 2; t2++) {
      const int gt = halfM * 2 + t2;
      // gate chains (consume af/ae)
      bf16x8 w0 = *(const bf16x8*)(W2e + (size_t)((gt * 2 + 0) * 64 + lane) * 8);
      bf16x8 w1 = *(const bf16x8*)(W2e + (size_t)((gt * 2 + 1) * 64 + lane) * 8);
      f32x16 G0 = __builtin_amdgcn_mfma_f32_32x32x16_bf16(ae[0], w0, (f32x16)(0.f), 0, 0, 0);
      f32x16 G1 = __builtin_amdgcn_mfma_f32_32x32x16_bf16(ae[1], w0, (f32x16)(0.f), 0, 0, 0);
      G0 = __builtin_amdgcn_mfma_f32_32x32x16_bf16(ae2[0], w1, G0, 0, 0, 0);
      G1 = __builtin_amdgcn_mfma_f32_32x32x16_bf16(ae2[1], w1, G1, 0, 0, 0);
#pragma unroll
      for (int ks = 0; ks < 8; ks++) {
        bf16x8 bg = *(const bf16x8*)(Bgh + (size_t)((gt * 16 + ks) * 64 + lane) * 8);
        G0 = __builtin_amdgcn_mfma_f32_32x32x16_bf16(af0[ks], bg, G0, 0, 0, 0);
        G1 = __builtin_amdgcn_mfma_f32_32x32x16_bf16(af1[ks], bg, G1, 0, 0, 0);
      }
      float g0[16], g1[16];
#pragma unroll
      for (int r = 0; r < 16; r++) {
        g0[r] = __builtin_amdgcn_rcpf(1.f + __expf(-G0[r]));
        g1[r] = __builtin_amdgcn_rcpf(1.f + __expf(-G1[r]));
      }
      // msg chains (consume a2)
      f32x16 M0 = (f32x16)(0.f), M1 = (f32x16)(0.f);
#pragma unroll
      for (int ks = 0; ks < 8; ks++) {
        bf16x8 bm = *(const bf16x8*)(Bm2 + (size_t)((gt * 8 + ks) * 64 + lane) * 8);
        M0 = __builtin_amdgcn_mfma_f32_32x32x16_bf16(a2_0[ks], bm, M0, 0, 0, 0);
        M1 = __builtin_amdgcn_mfma_f32_32x32x16_bf16(a2_1[ks], bm, M1, 0, 0, 0);
      }
      const float mb2 = mbias2[gt * 32 + c31];
      const int c2 = t2 * 32 + c31;
#pragma unroll
      for (int r = 0; r < 16; r++) {
        int row = (r & 3) + 8 * (r >> 2) + 4 * halfl;
        float m0 = g0[r] * (M0[r] + mb2);
        float m1 = g1[r] * (M1[r] + mb2);
        unsigned u0 = __float_as_uint(m0), u1 = __float_as_uint(m1);
        *(short2*)&R[row * 136 + c2 * 2] =
            make_short2((short)(u0 & 0xffff), (short)(u0 >> 16));
        *(short2*)&R[(32 + row) * 136 + c2 * 2] =
            make_short2((short)(u1 & 0xffff), (short)(u1 >> 16));
      }
    }
    // flush: lane owns column (halfM*64 + lane); run-reduce 64 sorted rows
    const int colg = halfM * 64 + lane;
    int cur = dsts[wave][0];
    float run = lds_f32(&R[lane * 2]);
#pragma unroll
    for (int row = 1; row < 64; row++) {
      int d = dsts[wave][row];
      float v = lds_f32(&R[row * 136 + lane * 2]);
      if (d == cur) {
        run += v;
      } else {
        atomicAdd(&agg[(size_t)cur * H + colg], run);
        cur = d; run = v;
      }
    }
    atomicAdd(&agg[(size_t)cur * H + colg], run);
  }
}

// ---------------- K4: node update via MFMA (16x16x32, R3 exact) --------------
__global__ __launch_bounds__(256) void k_node_up2(
    float* agg, const short* __restrict__ h_bf_in,
    const float* __restrict__ h_in,
    const short* __restrict__ Brs1, const short* __restrict__ Brs2,
    const float* __restrict__ rb1, const float* __restrict__ rb2,
    const float* __restrict__ lng, const float* __restrict__ lnb,
    float* __restrict__ h, short* __restrict__ h_bf) {
  __shared__ short regn[4][16 * 136];
  const int tid = threadIdx.x;
  const int wave = tid >> 6, lane = tid & 63;
  const int n0 = blockIdx.x * 64 + wave * 16;
  short* R = regn[wave];
  const int mrow = lane & 15, quad = lane >> 4;

  int nr = n0 + mrow; if (nr >= NN) nr = NN - 1;
  bf16x8 af[8];
#pragma unroll
  for (int ks = 0; ks < 4; ks++)
    af[ks] = *(const bf16x8*)(h_bf_in + (size_t)nr * H + ks * 32 + quad * 8);
#pragma unroll
  for (int ks = 0; ks < 4; ks++) {
    float4 u = *(const float4*)(agg + (size_t)nr * H + ks * 32 + quad * 8);
    float4 w = *(const float4*)(agg + (size_t)nr * H + ks * 32 + quad * 8 + 4);
    short tmp[8];
    tmp[0]=bf16rne(u.x); tmp[1]=bf16rne(u.y); tmp[2]=bf16rne(u.z); tmp[3]=bf16rne(u.w);
    tmp[4]=bf16rne(w.x); tmp[5]=bf16rne(w.y); tmp[6]=bf16rne(w.z); tmp[7]=bf16rne(w.w);
    af[4 + ks] = *(bf16x8*)tmp;
  }
  float4 z4 = make_float4(0.f, 0.f, 0.f, 0.f);
#pragma unroll
  for (int ks = 0; ks < 4; ks++) {
    *(float4*)(agg + (size_t)nr * H + ks * 32 + quad * 8) = z4;
    *(float4*)(agg + (size_t)nr * H + ks * 32 + quad * 8 + 4) = z4;
  }

#pragma unroll
  for (int t = 0; t < 8; t++) {
    f32x4 a = (f32x4){0.f, 0.f, 0.f, 0.f};
#pragma unroll
    for (int ks = 0; ks < 8; ks++) {
      bf16x8 bf = *(const bf16x8*)(Brs1 + (size_t)((t * 8 + ks) * 64 + lane) * 8);
      a = __builtin_amdgcn_mfma_f32_16x16x32_bf16(af[ks], bf, a, 0, 0, 0);
    }
    int col = t * 16 + mrow;
    float b = rb1[col];
#pragma unroll
    for (int r = 0; r < 4; r++)
      R[(quad * 4 + r) * 136 + col] = bf16rne(fmaxf(a[r] + b, 0.f));
  }
  bf16x8 a2[4];
#pragma unroll
  for (int ks = 0; ks < 4; ks++)
    a2[ks] = *(const bf16x8*)&R[mrow * 136 + ks * 32 + quad * 8];

  float vals[8][4];
  float gl[8], bl[8];
#pragma unroll
  for (int t = 0; t < 8; t++) {
    f32x4 a = (f32x4){0.f, 0.f, 0.f, 0.f};
#pragma unroll
    for (int ks = 0; ks < 4; ks++) {
      bf16x8 bf = *(const bf16x8*)(Brs2 + (size_t)((t * 4 + ks) * 64 + lane) * 8);
      a = __builtin_amdgcn_mfma_f32_16x16x32_bf16(a2[ks], bf, a, 0, 0, 0);
    }
    int col = t * 16 + mrow;
    float b2 = rb2[col];
    gl[t] = lng[col]; bl[t] = lnb[col];
#pragma unroll
    for (int r = 0; r < 4; r++) {
      int rowi = n0 + quad * 4 + r;
      int rl = rowi < NN ? rowi : NN - 1;
      vals[t][r] = h_in[(size_t)rl * H + col] + a[r] + b2;
    }
  }
#pragma unroll
  for (int r = 0; r < 4; r++) {
    float s1 = 0.f, s2 = 0.f;
#pragma unroll
    for (int t = 0; t < 8; t++) {
      s1 += vals[t][r];
      s2 = fmaf(vals[t][r], vals[t][r], s2);
    }
#pragma unroll
    for (int m = 1; m < 16; m <<= 1) {
      s1 += __shfl_xor(s1, m, 64);
      s2 += __shfl_xor(s2, m, 64);
    }
    float mean = s1 * (1.f / 128.f);
    float var = s2 * (1.f / 128.f) - mean * mean;
    float rs = rsqrtf(var + LEPS);
    int rowi = n0 + quad * 4 + r;
    if (rowi < NN) {
#pragma unroll
      for (int t = 0; t < 8; t++) {
        int col = t * 16 + mrow;
        float o = (vals[t][r] - mean) * rs * gl[t] + bl[t];
        h[(size_t)rowi * H + col] = o;
        h_bf[(size_t)rowi * H + col] = bf16rne(o);
      }
    }
  }
}

// ---------------- K5: pooling, run-reduce over sorted batch ----------------
__global__ __launch_bounds__(256) void k_pool(
    const float* __restrict__ h, const int* __restrict__ batch,
    float* __restrict__ gsum, float* __restrict__ gcnt) {
  const int tid = threadIdx.x;
  const int col = tid & 127, half = tid >> 7;
  int n0 = blockIdx.x * 32 + half * 16;
  if (n0 >= NN) return;
  int end = n0 + 16; if (end > NN) end = NN;
  int cur = batch[n0];
  float run = h[(size_t)n0 * H + col];
  float cnt = 1.f;
  for (int n = n0 + 1; n < end; n++) {
    int b = batch[n];
    float v = h[(size_t)n * H + col];
    if (b == cur) { run += v; cnt += 1.f; }
    else {
      atomicAdd(&gsum[(size_t)cur * H + col], run);
      if (col == 0) atomicAdd(&gcnt[cur], cnt);
      cur = b; run = v; cnt = 1.f;
    }
  }
  atomicAdd(&gsum[(size_t)cur * H + col], run);
  if (col == 0) atomicAdd(&gcnt[cur], cnt);
}

// ---------------- K6: readout MLP ----------------
__global__ __launch_bounds__(128) void k_readout(
    const float* __restrict__ gsum, const float* __restrict__ gcnt,
    const float* __restrict__ W1, const float* __restrict__ b1,
    const float* __restrict__ W2, const float* __restrict__ b2,
    float* __restrict__ out) {
  __shared__ float gs[H];
  __shared__ float o1[H];
  int b = blockIdx.x, c = threadIdx.x;
  float cnt = fmaxf(gcnt[b], 1.f);
  gs[c] = gsum[b * H + c] / cnt;
  __syncthreads();
  float acc = b1[c];
  for (int k = 0; k < H; k++) acc = fmaf(gs[k], W1[k * H + c], acc);
  o1[c] = fmaxf(acc, 0.f);
  __syncthreads();
  if (c < 2) {
    float acc2 = b2[c];
    for (int k = 0; k < H; k++) acc2 = fmaf(o1[k], W2[k * 2 + c], acc2);
    out[b * 2 + c] = acc2;
  }
}

extern "C" void kernel_launch(void* const* d_in, const int* in_sizes, int n_in,
                              void* d_out, int out_size, void* d_ws, size_t ws_size,
                              hipStream_t stream) {
  (void)in_sizes; (void)n_in; (void)out_size; (void)ws_size;
  const float* x       = (const float*)d_in[0];
  const float* ea      = (const float*)d_in[1];
  const int*   eidx    = (const int*)d_in[2];
  const int*   batch   = (const int*)d_in[3];
  const float* n_enc_w = (const float*)d_in[4];
  const float* n_enc_b = (const float*)d_in[5];
  const float* e_enc_w = (const float*)d_in[6];
  const float* e_enc_b = (const float*)d_in[7];
  const float* n_ln_g  = (const float*)d_in[8];
  const float* n_ln_b  = (const float*)d_in[9];
  const float* e_ln_g  = (const float*)d_in[10];
  const float* e_ln_b  = (const float*)d_in[11];
  const float* msg_w1  = (const float*)d_in[12];
  const float* msg_b1  = (const float*)d_in[13];
  const float* msg_w2  = (const float*)d_in[14];
  const float* msg_b2  = (const float*)d_in[15];
  const float* gate_w  = (const float*)d_in[16];
  const float* gate_b  = (const float*)d_in[17];
  const float* res_w1  = (const float*)d_in[18];
  const float* res_b1  = (const float*)d_in[19];
  const float* res_w2  = (const float*)d_in[20];
  const float* res_b2  = (const float*)d_in[21];
  const float* ln_g    = (const float*)d_in[22];
  const float* ln_b    = (const float*)d_in[23];
  const float* ro_w1   = (const float*)d_in[24];
  const float* ro_b1   = (const float*)d_in[25];
  const float* ro_w2   = (const float*)d_in[26];
  const float* ro_b2   = (const float*)d_in[27];

  char* p = (char*)d_ws;
  float* h     = (float*)p;  p += (size_t)NN * H * 4;          // 25.6 MB
  short* h_bf  = (short*)p;  p += (size_t)NN * H * 2;          // 12.8 MB
  float* agg   = (float*)p;  p += (size_t)NN * H * 4;          // 25.6 MB
  short* ea_bf = (short*)p;  p += (size_t)NE * EIN * 2;        // 25.6 MB
  float2* rsmu = (float2*)p; p += (size_t)NE * 8;              // 6.4 MB
  float* gsum  = (float*)p;  p += (size_t)NG * H * 4;
  float* gcnt  = (float*)p;  p += 1024;
  short* bgh   = (short*)p;  p += (size_t)3 * 65536 * 2;
  short* bm2   = (short*)p;  p += (size_t)3 * 16384 * 2;
  short* brs1  = (short*)p;  p += (size_t)3 * 32768 * 2;
  short* brs2  = (short*)p;  p += (size_t)3 * 16384 * 2;
  short* w2e   = (short*)p;  p += (size_t)3 * 8192 * 2;
  float* stats = (float*)p;  p += 2048;
  unsigned* rowptr = (unsigned*)p; p += ((size_t)NN * 4 + 15) / 16 * 16;
  unsigned* cursor = (unsigned*)p; p += ((size_t)NN * 4 + 15) / 16 * 16;
  int* src_s   = (int*)p;    p += (size_t)NE * 4;
  int* dst_s   = (int*)p;    p += (size_t)NE * 4;
  // total ~103 MB (L3-resident working set)

  const int node_blocks = (NN + 31) / 32;
  const int nup_blocks  = (NN + 63) / 64;   // 782
  const int edge_blocks = NE / 256;         // 3125, exact
  const int e256 = (NE + 255) / 256;        // 3125, exact
  const int conv_total = 3 * 65536 + 3 * 16384 + 3 * 32768 + 3 * 16384;
  const int fold_total = 3 * 8192 + 290;

  hipMemsetAsync(cursor, 0, (size_t)NN * 4, stream);
  k_fold<<<(fold_total + 255) / 256, 256, 0, stream>>>(
      gate_w, msg_w1, gate_b, msg_b1, e_enc_w, e_enc_b, e_ln_g, e_ln_b,
      w2e, stats);
  k_count<<<e256, 256, 0, stream>>>(eidx, cursor);
  k_scan<<<1, 1024, 0, stream>>>(cursor, rowptr);
  hipMemsetAsync(cursor, 0, (size_t)NN * 4, stream);
  k_scatter<<<e256, 256, 0, stream>>>(eidx, ea, rowptr, cursor, stats,
                                      src_s, dst_s, ea_bf, rsmu);

  k_convert_w<<<(conv_total + 255) / 256, 256, 0, stream>>>(
      gate_w, msg_w1, msg_w2, res_w1, res_w2,
      bgh, bm2, brs1, brs2);
  k_node_encode<<<node_blocks, 256, 0, stream>>>(x, n_enc_w, n_enc_b, n_ln_g, n_ln_b, h, h_bf);

  // agg zeroed once here; k_node_up2 re-zeroes it for the next layer
  hipMemsetAsync(agg, 0, (size_t)NN * H * 4, stream);
  for (int l = 0; l < NL; l++) {
    k_edge_mfma<<<edge_blocks, 256, 0, stream>>>(
        ea_bf, rsmu, src_s, dst_s, h_bf,
        bgh + (size_t)l * 65536, bm2 + (size_t)l * 16384,
        w2e + (size_t)l * 8192, msg_b2 + l * H, agg);
    k_node_up2<<<nup_blocks, 256, 0, stream>>>(
        agg, h_bf, h,
        brs1 + (size_t)l * 32768, brs2 + (size_t)l * 16384,
        res_b1 + l * H, res_b2 + l * H,
        ln_g + l * H, ln_b + l * H, h, h_bf);
  }

  hipMemsetAsync(gsum, 0, ((size_t)NG * H + NG) * 4, stream);
  k_pool<<<(NN + 31) / 32, 256, 0, stream>>>(h, batch, gsum, gcnt);
  k_readout<<<NG, 128, 0, stream>>>(gsum, gcnt, ro_w1, ro_b1, ro_w2, ro_b2, (float*)d_out);
}

// Round 6
// 1062.979 us; speedup vs baseline: 1.3661x; 1.3661x over previous
//
#include <hip/hip_runtime.h>
#include <hip/hip_bf16.h>
#include <math.h>

#define NN 50000
#define NE 800000
#define NG 256
#define H 128
#define NIN 64
#define EIN 16
#define NL 3
#define LEPS 1e-5f

typedef short bf16x8 __attribute__((ext_vector_type(8)));
typedef float f32x4 __attribute__((ext_vector_type(4)));
typedef float f32x16 __attribute__((ext_vector_type(16)));
typedef unsigned u32x4 __attribute__((ext_vector_type(4)));

__device__ __forceinline__ short bf16rne(float x) {
  unsigned u = __float_as_uint(x);
  unsigned r = u + 0x7fff + ((u >> 16) & 1);
  return (short)(r >> 16);
}

// pack two floats to bf16 pair (lo in low short) — RNE, same bits as bf16rne
__device__ __forceinline__ unsigned pk2(float lo, float hi) {
  __hip_bfloat162 h = __float22bfloat162_rn(make_float2(lo, hi));
  return *(unsigned*)&h;
}

__device__ __forceinline__ float wsum(float v) {
#pragma unroll
  for (int m = 1; m < 64; m <<= 1) v += __shfl_xor(v, m, 64);
  return v;
}

// ---------------- sort-by-dst pipeline (once per launch) ----------------
__global__ __launch_bounds__(256) void k_count(const int* __restrict__ eidx,
                                               unsigned* __restrict__ cnt) {
  int t = blockIdx.x * 256 + threadIdx.x;
  if (t < NE) atomicAdd(&cnt[eidx[NE + t]], 1u);
}

__global__ __launch_bounds__(1024) void k_scan(const unsigned* __restrict__ cnt,
                                               unsigned* __restrict__ rowptr) {
  __shared__ unsigned part[16];
  __shared__ unsigned carry_s;
  const int tid = threadIdx.x, lane = tid & 63, wid = tid >> 6;
  if (tid == 0) carry_s = 0;
  __syncthreads();
  for (int base = 0; base < NN; base += 1024) {
    int i = base + tid;
    unsigned v = (i < NN) ? cnt[i] : 0u;
    unsigned incl = v;
#pragma unroll
    for (int off = 1; off < 64; off <<= 1) {
      unsigned t = __shfl_up(incl, off, 64);
      if (lane >= off) incl += t;
    }
    if (lane == 63) part[wid] = incl;
    __syncthreads();
    if (tid == 0) {
      unsigned s = 0;
#pragma unroll
      for (int w = 0; w < 16; w++) { unsigned t = part[w]; part[w] = s; s += t; }
    }
    __syncthreads();
    unsigned carry = carry_s;
    if (i < NN) rowptr[i] = carry + part[wid] + incl - v;
    __syncthreads();
    if (tid == 1023) carry_s = carry + part[15] + incl;
    __syncthreads();
  }
}

// ---------------- K_fold: LN-fold precompute (once) --------------------------
// W2e_ext[l]: 32 k-rows x 256 n, bf16, B-frag layout (verified R4/R5):
//   f = nt*2 + ks2 (f<16): k<16 : We·diag(g)·Wbot ; k=16: (be∘g)@Wbot ;
//   k=17: g@Wbot ; k=18: b_ln@Wbot + out-bias (gate_b | msg_b1) ; k>18: 0.
// stats: M[16][16]=We·We^T, wcs[16]=rowsum(We), v[16]=We@be, cc=Σbe², sbe=Σbe
__global__ __launch_bounds__(256) void k_fold(
    const float* __restrict__ gate_w, const float* __restrict__ msg_w1,
    const float* __restrict__ gate_b, const float* __restrict__ msg_b1,
    const float* __restrict__ e_enc_w, const float* __restrict__ e_enc_b,
    const float* __restrict__ e_ln_g, const float* __restrict__ e_ln_b,
    short* __restrict__ w2e, float* __restrict__ stats) {
  const int S_W2E = 3 * 8192;
  const int S_ST = S_W2E + 290;
  int tid = blockIdx.x * 256 + threadIdx.x;
  if (tid >= S_ST) return;
  if (tid < S_W2E) {
    int l = tid / 8192, e = tid % 8192;
    int f = e >> 9, lane = (e >> 3) & 63, j = e & 7;
    int nt = f >> 1, ks2 = f & 1;
    int k = ks2 * 16 + (lane >> 5) * 8 + j;
    int n = nt * 32 + (lane & 31);
    float s = 0.f;
    if (k < 19) {
      for (int m = 0; m < 128; m++) {
        float w = (n < 128) ? gate_w[((size_t)l * 256 + 128 + m) * 128 + n]
                            : msg_w1[((size_t)l * 256 + 128 + m) * 128 + (n - 128)];
        float fm = (k < 16)   ? e_enc_w[k * 128 + m] * e_ln_g[m]
                 : (k == 16)  ? e_enc_b[m] * e_ln_g[m]
                 : (k == 17)  ? e_ln_g[m]
                              : e_ln_b[m];
        s += fm * w;
      }
      if (k == 18)
        s += (n < 128) ? gate_b[l * 128 + n] : msg_b1[l * 128 + (n - 128)];
    }
    w2e[tid] = bf16rne(s);
  } else {
    int e = tid - S_W2E;
    if (e < 256) {
      int i = e >> 4, j = e & 15;
      float s = 0.f;
      for (int n = 0; n < 128; n++)
        s += e_enc_w[i * 128 + n] * e_enc_w[j * 128 + n];
      stats[e] = s;
    } else if (e < 272) {
      int k = e - 256;
      float s = 0.f;
      for (int n = 0; n < 128; n++) s += e_enc_w[k * 128 + n];
      stats[e] = s;
    } else if (e < 288) {
      int k = e - 272;
      float s = 0.f;
      for (int n = 0; n < 128; n++) s += e_enc_w[k * 128 + n] * e_enc_b[n];
      stats[e] = s;
    } else if (e == 288) {
      float s = 0.f;
      for (int n = 0; n < 128; n++) s += e_enc_b[n] * e_enc_b[n];
      stats[e] = s;
    } else {
      float s = 0.f;
      for (int n = 0; n < 128; n++) s += e_enc_b[n];
      stats[e] = s;
    }
  }
}

// ---------------- k_scatter: sort edges + bf16 ea + per-edge LN stats --------
__global__ __launch_bounds__(256) void k_scatter(
    const int* __restrict__ eidx, const float* __restrict__ ea,
    const unsigned* __restrict__ rowptr, unsigned* __restrict__ cursor,
    const float* __restrict__ stats,
    int* __restrict__ src_s, int* __restrict__ dst_s,
    short* __restrict__ ea_bf, float2* __restrict__ rsmu) {
  __shared__ float S[290];
  for (int i = threadIdx.x; i < 290; i += 256) S[i] = stats[i];
  __syncthreads();
  int t = blockIdx.x * 256 + threadIdx.x;
  int s = eidx[t], d = eidx[NE + t];
  unsigned pos = rowptr[d] + atomicAdd(&cursor[d], 1u);
  src_s[pos] = s;
  dst_s[pos] = d;
  const float4* er = (const float4*)(ea + (size_t)t * EIN);
  float4 q0 = er[0], q1 = er[1], q2 = er[2], q3 = er[3];
  float e16[16];
  e16[0]=q0.x; e16[1]=q0.y; e16[2]=q0.z; e16[3]=q0.w;
  e16[4]=q1.x; e16[5]=q1.y; e16[6]=q1.z; e16[7]=q1.w;
  e16[8]=q2.x; e16[9]=q2.y; e16[10]=q2.z; e16[11]=q2.w;
  e16[12]=q3.x; e16[13]=q3.y; e16[14]=q3.z; e16[15]=q3.w;
  short tmp[16];
#pragma unroll
  for (int j = 0; j < 16; j++) tmp[j] = bf16rne(e16[j]);
  short* dstp = ea_bf + (size_t)pos * EIN;
  *(bf16x8*)dstp = *(bf16x8*)tmp;
  *(bf16x8*)(dstp + 8) = *(bf16x8*)(tmp + 8);
  // LN stats (exact fp32)
  float s1 = S[289], s2 = S[288];
#pragma unroll
  for (int k = 0; k < 16; k++) {
    s1 = fmaf(e16[k], S[256 + k], s1);
    s2 = fmaf(2.f * e16[k], S[272 + k], s2);
  }
#pragma unroll
  for (int i = 0; i < 16; i++) {
    float mi = 0.f;
#pragma unroll
    for (int j = 0; j < 16; j++) mi = fmaf(S[i * 16 + j], e16[j], mi);
    s2 = fmaf(e16[i], mi, s2);
  }
  float mu = s1 * (1.f / 128.f);
  float var = s2 * (1.f / 128.f) - mu * mu;
  float rs = rsqrtf(var + LEPS);
  rsmu[pos] = make_float2(rs, mu);
}

// ---------------- K0: pre-swizzle weights -----------------------------------
__global__ __launch_bounds__(256) void k_convert_w(
    const float* __restrict__ gate_w, const float* __restrict__ msg_w1,
    const float* __restrict__ msg_w2, const float* __restrict__ res_w1,
    const float* __restrict__ res_w2,
    short* __restrict__ bgh, short* __restrict__ bm2,
    short* __restrict__ brs1, short* __restrict__ brs2) {
  const int S_BGH = 3 * 65536;
  const int S_BM2 = S_BGH + 3 * 16384;
  const int S_BR1 = S_BM2 + 3 * 32768;
  const int S_BR2 = S_BR1 + 3 * 16384;
  int tid = blockIdx.x * 256 + threadIdx.x;
  if (tid >= S_BR2) return;
  if (tid < S_BGH) {
    int l = tid / 65536, e = tid % 65536;
    int f = e >> 9, lane = (e >> 3) & 63, j = e & 7;
    int nt = f >> 4, ks = f & 15;
    int k = ks * 16 + (lane >> 5) * 8 + j;
    int n = nt * 32 + (lane & 31);
    float v = (n < 128) ? gate_w[((size_t)l * 256 + k) * 128 + n]
                        : msg_w1[((size_t)l * 256 + k) * 128 + (n - 128)];
    bgh[tid] = bf16rne(v);
  } else if (tid < S_BM2) {
    int e0 = tid - S_BGH;
    int l = e0 / 16384, e = e0 % 16384;
    int f = e >> 9, lane = (e >> 3) & 63, j = e & 7;
    int nt = f >> 3, ks = f & 7;
    int k = ks * 16 + (lane >> 5) * 8 + j;
    int n = nt * 32 + (lane & 31);
    bm2[e0] = bf16rne(msg_w2[((size_t)l * 128 + k) * 128 + n]);
  } else if (tid < S_BR1) {
    int e0 = tid - S_BM2;
    int l = e0 / 32768, e = e0 % 32768;
    int f = e >> 9, lane = (e >> 3) & 63, j = e & 7;
    int nt = f >> 3, ks = f & 7;
    int k = ks * 32 + (lane >> 4) * 8 + j;
    int n = nt * 16 + (lane & 15);
    brs1[e0] = bf16rne(res_w1[((size_t)l * 256 + k) * 128 + n]);
  } else {
    int e0 = tid - S_BR1;
    int l = e0 / 16384, e = e0 % 16384;
    int f = e >> 9, lane = (e >> 3) & 63, j = e & 7;
    int nt = f >> 2, ks = f & 3;
    int k = ks * 32 + (lane >> 4) * 8 + j;
    int n = nt * 16 + (lane & 15);
    brs2[e0] = bf16rne(res_w2[((size_t)l * 128 + k) * 128 + n]);
  }
}

// ---------------- K1: h = LN(x @ Wn + bn), also emit bf16 copy ----------------
__global__ __launch_bounds__(256) void k_node_encode(
    const float* __restrict__ x, const float* __restrict__ W,
    const float* __restrict__ bias,
    const float* __restrict__ lng, const float* __restrict__ lnb,
    float* __restrict__ h, short* __restrict__ h_bf) {
  __shared__ float xs[4][8 * NIN];
  const int wave = threadIdx.x >> 6, lane = threadIdx.x & 63;
  const int n0 = (blockIdx.x * 4 + wave) * 8;
  float* xt = xs[wave];
  for (int i = lane; i < 8 * NIN; i += 64) {
    int idx = n0 * NIN + i;
    xt[i] = (idx < NN * NIN) ? x[idx] : 0.f;
  }
  __syncthreads();
  const int c0 = lane, c1 = lane + 64;
  float a0[8], a1[8];
#pragma unroll
  for (int j = 0; j < 8; j++) { a0[j] = 0.f; a1[j] = 0.f; }
  for (int k = 0; k < NIN; k++) {
    float w0 = W[k * H + c0], w1 = W[k * H + c1];
#pragma unroll
    for (int j = 0; j < 8; j++) {
      float xv = xt[j * NIN + k];
      a0[j] = fmaf(xv, w0, a0[j]);
      a1[j] = fmaf(xv, w1, a1[j]);
    }
  }
  const float b0 = bias[c0], b1 = bias[c1];
  const float g0 = lng[c0], g1 = lng[c1], lb0 = lnb[c0], lb1 = lnb[c1];
#pragma unroll
  for (int j = 0; j < 8; j++) {
    float v0 = a0[j] + b0, v1 = a1[j] + b1;
    float mean = wsum(v0 + v1) * (1.f / H);
    float d0 = v0 - mean, d1 = v1 - mean;
    float var = wsum(d0 * d0 + d1 * d1) * (1.f / H);
    float rs = rsqrtf(var + LEPS);
    int n = n0 + j;
    if (n < NN) {
      float o0 = d0 * rs * g0 + lb0, o1 = d1 * rs * g1 + lb1;
      h[n * H + c0] = o0;
      h[n * H + c1] = o1;
      h_bf[n * H + c0] = bf16rne(o0);
      h_bf[n * H + c1] = bf16rne(o1);
    }
  }
}

// ---------------- K3: MFMA edge kernel, LDS-staged weights -------------------
// R3's per-wave structure (M=32 edges, K-row LN fold per R5) + block-level
// cooperative weight staging: the block's 4 waves share each tile's 8 weight
// fragments via a double-buffered LDS wbuf (each wave global-loads 2 frags to
// regs at iteration top — latency hides under the tile's 10-MFMA chain — and
// ds_writes them between two barriers at iteration end).  Cuts L2 weight
// traffic 4x (2.8 GB -> 0.7 GB per dispatch; R3 was ~81 us of L2 BW on weight
// re-reads).  W2e (2 small frags/tile) stays direct-from-L2.
// Tile order: H4 H5 H6 H7 | G0 M0 G1 M1 G2 M2 G3 M3 (gate live range = 16).
// C/D: col=lane&31, row=(reg&3)+8*(reg>>2)+4*(lane>>5).  A/B: m/n=lane&31,
// k=(lane>>5)*8+j.  Staged-frag LDS reads are lane-linear (0 bank conflicts).
__global__ __launch_bounds__(256) void k_edge_mfma(
    const short* __restrict__ ea_bf, const float2* __restrict__ rsmu,
    const int* __restrict__ src_s, const int* __restrict__ dst_s,
    const short* __restrict__ h_bf,
    const short* __restrict__ Bgh, const short* __restrict__ Bm2,
    const short* __restrict__ W2e, const float* __restrict__ mbias2,
    float* __restrict__ agg) {
  __shared__ short wbuf[2][4096];       // 8 frags/tile, dbuf: 16 KB
  __shared__ short regn[4][32 * 136];   // T2 + msg staging, 34.8 KB
  __shared__ int dsts[4][32];
  const int tid = threadIdx.x;
  const int wave = tid >> 6, lane = tid & 63;
  const int e0 = blockIdx.x * 128 + wave * 32;
  short* R = regn[wave];
  float* Rf = (float*)R;                // float view: Rf[row*68 + c]
  const int c31 = lane & 31, halfl = lane >> 5;
  const int koff = halfl * 8;
  const int soff0 = (2 * wave) * 512 + lane * 8;      // this wave's 2 frag slots
  const int soff1 = (2 * wave + 1) * 512 + lane * 8;

  if (lane < 32) dsts[wave][lane] = dst_s[e0 + lane];

  // ---- A operands ----
  const int srow = src_s[e0 + c31];
  bf16x8 af[8];
#pragma unroll
  for (int ks = 0; ks < 8; ks++)
    af[ks] = *(const bf16x8*)(h_bf + (size_t)srow * H + ks * 16 + koff);

  const float2 rm = rsmu[e0 + c31];
  bf16x8 ae;
  {
    bf16x8 raw = *(const bf16x8*)(ea_bf + (size_t)(e0 + c31) * EIN + koff);
    u32x4 v;
#pragma unroll
    for (int p = 0; p < 4; p++) {
      float lo = __uint_as_float(((unsigned)(unsigned short)raw[2 * p]) << 16) * rm.x;
      float hi = __uint_as_float(((unsigned)(unsigned short)raw[2 * p + 1]) << 16) * rm.x;
      v[p] = pk2(lo, hi);
    }
    ae = __builtin_bit_cast(bf16x8, v);
  }
  bf16x8 ae2;
  {
    u32x4 w;
    w[0] = halfl ? 0u : pk2(rm.x, -rm.x * rm.y);   // k16=rs, k17=-rs*mu
    w[1] = halfl ? 0u : 0x00003F80u;               // k18=1.0
    w[2] = 0u; w[3] = 0u;
    ae2 = __builtin_bit_cast(bf16x8, w);
  }

  // ---- tile source bases (shorts): H4..H7, G0,M0,G1,M1,G2,M2,G3,M3 ----
  // H_i -> Bgh + (4+i)*8192 ; G_j -> Bgh + j*8192 ; M_j -> Bm2 + j*4096
  // prologue: stage tile 0 (H4)
  {
    const short* s = Bgh + (size_t)4 * 8192;
    bf16x8 p0 = *(const bf16x8*)(s + soff0);
    bf16x8 p1 = *(const bf16x8*)(s + soff1);
    *(bf16x8*)&wbuf[0][soff0] = p0;
    *(bf16x8*)&wbuf[0][soff1] = p1;
  }
  __syncthreads();

  bf16x8 a2[8];
  float gate[16];
  bf16x8 sl0, sl1;

#pragma unroll
  for (int t = 0; t < 12; t++) {
    const int b = t & 1;
    // ---- issue next tile's stage loads (held in regs until iteration end) --
    if (t < 11) {
      const int tn = t + 1;
      const short* s;
      if (tn < 4) s = Bgh + (size_t)(4 + tn) * 8192;
      else if (((tn - 4) & 1) == 0) s = Bgh + (size_t)((tn - 4) >> 1) * 8192;
      else s = Bm2 + (size_t)((tn - 4) >> 1) * 4096;
      sl0 = *(const bf16x8*)(s + soff0);
      sl1 = *(const bf16x8*)(s + soff1);
    }
    // ---- compute tile t from wbuf[b] ----
    if (t < 4) {                       // hidden nt = 4+t
      const int nt = 4 + t;
      f32x16 a = __builtin_amdgcn_mfma_f32_32x32x16_bf16(
          ae, *(const bf16x8*)(W2e + (size_t)((nt * 2 + 0) * 64 + lane) * 8),
          (f32x16)(0.f), 0, 0, 0);
      a = __builtin_amdgcn_mfma_f32_32x32x16_bf16(
          ae2, *(const bf16x8*)(W2e + (size_t)((nt * 2 + 1) * 64 + lane) * 8),
          a, 0, 0, 0);
#pragma unroll
      for (int ks = 0; ks < 8; ks++)
        a = __builtin_amdgcn_mfma_f32_32x32x16_bf16(
            af[ks], *(const bf16x8*)&wbuf[b][ks * 512 + lane * 8], a, 0, 0, 0);
      const int col = t * 32 + c31;
#pragma unroll
      for (int r = 0; r < 16; r++) {
        int row = (r & 3) + 8 * (r >> 2) + 4 * halfl;
        R[row * 136 + col] = bf16rne(fmaxf(a[r], 0.f));
      }
      if (t == 3) {                    // snapshot GEMM2 A-frags from T2
#pragma unroll
        for (int ks = 0; ks < 8; ks++)
          a2[ks] = *(const bf16x8*)&R[c31 * 136 + ks * 16 + koff];
      }
    } else if (((t - 4) & 1) == 0) {   // gate gt = (t-4)/2
      const int gt = (t - 4) >> 1;
      f32x16 a = __builtin_amdgcn_mfma_f32_32x32x16_bf16(
          ae, *(const bf16x8*)(W2e + (size_t)((gt * 2 + 0) * 64 + lane) * 8),
          (f32x16)(0.f), 0, 0, 0);
      a = __builtin_amdgcn_mfma_f32_32x32x16_bf16(
          ae2, *(const bf16x8*)(W2e + (size_t)((gt * 2 + 1) * 64 + lane) * 8),
          a, 0, 0, 0);
#pragma unroll
      for (int ks = 0; ks < 8; ks++)
        a = __builtin_amdgcn_mfma_f32_32x32x16_bf16(
            af[ks], *(const bf16x8*)&wbuf[b][ks * 512 + lane * 8], a, 0, 0, 0);
#pragma unroll
      for (int r = 0; r < 16; r++)
        gate[r] = __builtin_amdgcn_rcpf(1.f + __expf(-a[r]));
    } else {                           // msg gt = (t-4)/2
      const int gt = (t - 4) >> 1;
      const int t2 = gt & 1;
      f32x16 m = (f32x16)(0.f);
#pragma unroll
      for (int ks = 0; ks < 8; ks++)
        m = __builtin_amdgcn_mfma_f32_32x32x16_bf16(
            a2[ks], *(const bf16x8*)&wbuf[b][ks * 512 + lane * 8], m, 0, 0, 0);
      const float mb2 = mbias2[gt * 32 + c31];
      const int c2 = t2 * 32 + c31;
#pragma unroll
      for (int r = 0; r < 16; r++) {
        int row = (r & 3) + 8 * (r >> 2) + 4 * halfl;
        Rf[row * 68 + c2] = gate[r] * (m[r] + mb2);
      }
      if (t == 7 || t == 11) {
        // flush: lane owns column (hM*64 + lane); run-reduce 32 sorted rows
        const int hM = (t == 11);
        const int colg = hM * 64 + lane;
        int cur = dsts[wave][0];
        float run = Rf[lane];
#pragma unroll
        for (int row = 1; row < 32; row++) {
          int d = dsts[wave][row];
          float v = Rf[row * 68 + lane];
          if (d == cur) {
            run += v;
          } else {
            atomicAdd(&agg[(size_t)cur * H + colg], run);
            cur = d; run = v;
          }
        }
        atomicAdd(&agg[(size_t)cur * H + colg], run);
      }
    }
    // ---- stage write (barrier-protected, dbuf) ----
    if (t < 11) {
      __syncthreads();                 // all waves done reading wbuf[b^1] (t-1)
      *(bf16x8*)&wbuf[b ^ 1][soff0] = sl0;
      *(bf16x8*)&wbuf[b ^ 1][soff1] = sl1;
      __syncthreads();                 // tile t+1 data visible to all
    }
  }
}

// ---------------- K4: node update via MFMA (16x16x32, R3 exact) --------------
__global__ __launch_bounds__(256) void k_node_up2(
    float* agg, const short* __restrict__ h_bf_in,
    const float* __restrict__ h_in,
    const short* __restrict__ Brs1, const short* __restrict__ Brs2,
    const float* __restrict__ rb1, const float* __restrict__ rb2,
    const float* __restrict__ lng, const float* __restrict__ lnb,
    float* __restrict__ h, short* __restrict__ h_bf) {
  __shared__ short regn[4][16 * 136];
  const int tid = threadIdx.x;
  const int wave = tid >> 6, lane = tid & 63;
  const int n0 = blockIdx.x * 64 + wave * 16;
  short* R = regn[wave];
  const int mrow = lane & 15, quad = lane >> 4;

  int nr = n0 + mrow; if (nr >= NN) nr = NN - 1;
  bf16x8 af[8];
#pragma unroll
  for (int ks = 0; ks < 4; ks++)
    af[ks] = *(const bf16x8*)(h_bf_in + (size_t)nr * H + ks * 32 + quad * 8);
#pragma unroll
  for (int ks = 0; ks < 4; ks++) {
    float4 u = *(const float4*)(agg + (size_t)nr * H + ks * 32 + quad * 8);
    float4 w = *(const float4*)(agg + (size_t)nr * H + ks * 32 + quad * 8 + 4);
    short tmp[8];
    tmp[0]=bf16rne(u.x); tmp[1]=bf16rne(u.y); tmp[2]=bf16rne(u.z); tmp[3]=bf16rne(u.w);
    tmp[4]=bf16rne(w.x); tmp[5]=bf16rne(w.y); tmp[6]=bf16rne(w.z); tmp[7]=bf16rne(w.w);
    af[4 + ks] = *(bf16x8*)tmp;
  }
  float4 z4 = make_float4(0.f, 0.f, 0.f, 0.f);
#pragma unroll
  for (int ks = 0; ks < 4; ks++) {
    *(float4*)(agg + (size_t)nr * H + ks * 32 + quad * 8) = z4;
    *(float4*)(agg + (size_t)nr * H + ks * 32 + quad * 8 + 4) = z4;
  }

#pragma unroll
  for (int t = 0; t < 8; t++) {
    f32x4 a = (f32x4){0.f, 0.f, 0.f, 0.f};
#pragma unroll
    for (int ks = 0; ks < 8; ks++) {
      bf16x8 bf = *(const bf16x8*)(Brs1 + (size_t)((t * 8 + ks) * 64 + lane) * 8);
      a = __builtin_amdgcn_mfma_f32_16x16x32_bf16(af[ks], bf, a, 0, 0, 0);
    }
    int col = t * 16 + mrow;
    float b = rb1[col];
#pragma unroll
    for (int r = 0; r < 4; r++)
      R[(quad * 4 + r) * 136 + col] = bf16rne(fmaxf(a[r] + b, 0.f));
  }
  bf16x8 a2[4];
#pragma unroll
  for (int ks = 0; ks < 4; ks++)
    a2[ks] = *(const bf16x8*)&R[mrow * 136 + ks * 32 + quad * 8];

  float vals[8][4];
  float gl[8], bl[8];
#pragma unroll
  for (int t = 0; t < 8; t++) {
    f32x4 a = (f32x4){0.f, 0.f, 0.f, 0.f};
#pragma unroll
    for (int ks = 0; ks < 4; ks++) {
      bf16x8 bf = *(const bf16x8*)(Brs2 + (size_t)((t * 4 + ks) * 64 + lane) * 8);
      a = __builtin_amdgcn_mfma_f32_16x16x32_bf16(a2[ks], bf, a, 0, 0, 0);
    }
    int col = t * 16 + mrow;
    float b2 = rb2[col];
    gl[t] = lng[col]; bl[t] = lnb[col];
#pragma unroll
    for (int r = 0; r < 4; r++) {
      int rowi = n0 + quad * 4 + r;
      int rl = rowi < NN ? rowi : NN - 1;
      vals[t][r] = h_in[(size_t)rl * H + col] + a[r] + b2;
    }
  }
#pragma unroll
  for (int r = 0; r < 4; r++) {
    float s1 = 0.f, s2 = 0.f;
#pragma unroll
    for (int t = 0; t < 8; t++) {
      s1 += vals[t][r];
      s2 = fmaf(vals[t][r], vals[t][r], s2);
    }
#pragma unroll
    for (int m = 1; m < 16; m <<= 1) {
      s1 += __shfl_xor(s1, m, 64);
      s2 += __shfl_xor(s2, m, 64);
    }
    float mean = s1 * (1.f / 128.f);
    float var = s2 * (1.f / 128.f) - mean * mean;
    float rs = rsqrtf(var + LEPS);
    int rowi = n0 + quad * 4 + r;
    if (rowi < NN) {
#pragma unroll
      for (int t = 0; t < 8; t++) {
        int col = t * 16 + mrow;
        float o = (vals[t][r] - mean) * rs * gl[t] + bl[t];
        h[(size_t)rowi * H + col] = o;
        h_bf[(size_t)rowi * H + col] = bf16rne(o);
      }
    }
  }
}

// ---------------- K5: pooling, run-reduce over sorted batch ----------------
__global__ __launch_bounds__(256) void k_pool(
    const float* __restrict__ h, const int* __restrict__ batch,
    float* __restrict__ gsum, float* __restrict__ gcnt) {
  const int tid = threadIdx.x;
  const int col = tid & 127, half = tid >> 7;
  int n0 = blockIdx.x * 32 + half * 16;
  if (n0 >= NN) return;
  int end = n0 + 16; if (end > NN) end = NN;
  int cur = batch[n0];
  float run = h[(size_t)n0 * H + col];
  float cnt = 1.f;
  for (int n = n0 + 1; n < end; n++) {
    int b = batch[n];
    float v = h[(size_t)n * H + col];
    if (b == cur) { run += v; cnt += 1.f; }
    else {
      atomicAdd(&gsum[(size_t)cur * H + col], run);
      if (col == 0) atomicAdd(&gcnt[cur], cnt);
      cur = b; run = v; cnt = 1.f;
    }
  }
  atomicAdd(&gsum[(size_t)cur * H + col], run);
  if (col == 0) atomicAdd(&gcnt[cur], cnt);
}

// ---------------- K6: readout MLP ----------------
__global__ __launch_bounds__(128) void k_readout(
    const float* __restrict__ gsum, const float* __restrict__ gcnt,
    const float* __restrict__ W1, const float* __restrict__ b1,
    const float* __restrict__ W2, const float* __restrict__ b2,
    float* __restrict__ out) {
  __shared__ float gs[H];
  __shared__ float o1[H];
  int b = blockIdx.x, c = threadIdx.x;
  float cnt = fmaxf(gcnt[b], 1.f);
  gs[c] = gsum[b * H + c] / cnt;
  __syncthreads();
  float acc = b1[c];
  for (int k = 0; k < H; k++) acc = fmaf(gs[k], W1[k * H + c], acc);
  o1[c] = fmaxf(acc, 0.f);
  __syncthreads();
  if (c < 2) {
    float acc2 = b2[c];
    for (int k = 0; k < H; k++) acc2 = fmaf(o1[k], W2[k * 2 + c], acc2);
    out[b * 2 + c] = acc2;
  }
}

extern "C" void kernel_launch(void* const* d_in, const int* in_sizes, int n_in,
                              void* d_out, int out_size, void* d_ws, size_t ws_size,
                              hipStream_t stream) {
  (void)in_sizes; (void)n_in; (void)out_size; (void)ws_size;
  const float* x       = (const float*)d_in[0];
  const float* ea      = (const float*)d_in[1];
  const int*   eidx    = (const int*)d_in[2];
  const int*   batch   = (const int*)d_in[3];
  const float* n_enc_w = (const float*)d_in[4];
  const float* n_enc_b = (const float*)d_in[5];
  const float* e_enc_w = (const float*)d_in[6];
  const float* e_enc_b = (const float*)d_in[7];
  const float* n_ln_g  = (const float*)d_in[8];
  const float* n_ln_b  = (const float*)d_in[9];
  const float* e_ln_g  = (const float*)d_in[10];
  const float* e_ln_b  = (const float*)d_in[11];
  const float* msg_w1  = (const float*)d_in[12];
  const float* msg_b1  = (const float*)d_in[13];
  const float* msg_w2  = (const float*)d_in[14];
  const float* msg_b2  = (const float*)d_in[15];
  const float* gate_w  = (const float*)d_in[16];
  const float* gate_b  = (const float*)d_in[17];
  const float* res_w1  = (const float*)d_in[18];
  const float* res_b1  = (const float*)d_in[19];
  const float* res_w2  = (const float*)d_in[20];
  const float* res_b2  = (const float*)d_in[21];
  const float* ln_g    = (const float*)d_in[22];
  const float* ln_b    = (const float*)d_in[23];
  const float* ro_w1   = (const float*)d_in[24];
  const float* ro_b1   = (const float*)d_in[25];
  const float* ro_w2   = (const float*)d_in[26];
  const float* ro_b2   = (const float*)d_in[27];

  char* p = (char*)d_ws;
  float* h     = (float*)p;  p += (size_t)NN * H * 4;          // 25.6 MB
  short* h_bf  = (short*)p;  p += (size_t)NN * H * 2;          // 12.8 MB
  float* agg   = (float*)p;  p += (size_t)NN * H * 4;          // 25.6 MB
  short* ea_bf = (short*)p;  p += (size_t)NE * EIN * 2;        // 25.6 MB
  float2* rsmu = (float2*)p; p += (size_t)NE * 8;              // 6.4 MB
  float* gsum  = (float*)p;  p += (size_t)NG * H * 4;
  float* gcnt  = (float*)p;  p += 1024;
  short* bgh   = (short*)p;  p += (size_t)3 * 65536 * 2;
  short* bm2   = (short*)p;  p += (size_t)3 * 16384 * 2;
  short* brs1  = (short*)p;  p += (size_t)3 * 32768 * 2;
  short* brs2  = (short*)p;  p += (size_t)3 * 16384 * 2;
  short* w2e   = (short*)p;  p += (size_t)3 * 8192 * 2;
  float* stats = (float*)p;  p += 2048;
  unsigned* rowptr = (unsigned*)p; p += ((size_t)NN * 4 + 15) / 16 * 16;
  unsigned* cursor = (unsigned*)p; p += ((size_t)NN * 4 + 15) / 16 * 16;
  int* src_s   = (int*)p;    p += (size_t)NE * 4;
  int* dst_s   = (int*)p;    p += (size_t)NE * 4;
  // total ~103 MB (L3-resident working set)

  const int node_blocks = (NN + 31) / 32;
  const int nup_blocks  = (NN + 63) / 64;   // 782
  const int edge_blocks = NE / 128;         // 6250, exact
  const int e256 = (NE + 255) / 256;        // 3125, exact
  const int conv_total = 3 * 65536 + 3 * 16384 + 3 * 32768 + 3 * 16384;
  const int fold_total = 3 * 8192 + 290;

  hipMemsetAsync(cursor, 0, (size_t)NN * 4, stream);
  k_fold<<<(fold_total + 255) / 256, 256, 0, stream>>>(
      gate_w, msg_w1, gate_b, msg_b1, e_enc_w, e_enc_b, e_ln_g, e_ln_b,
      w2e, stats);
  k_count<<<e256, 256, 0, stream>>>(eidx, cursor);
  k_scan<<<1, 1024, 0, stream>>>(cursor, rowptr);
  hipMemsetAsync(cursor, 0, (size_t)NN * 4, stream);
  k_scatter<<<e256, 256, 0, stream>>>(eidx, ea, rowptr, cursor, stats,
                                      src_s, dst_s, ea_bf, rsmu);

  k_convert_w<<<(conv_total + 255) / 256, 256, 0, stream>>>(
      gate_w, msg_w1, msg_w2, res_w1, res_w2,
      bgh, bm2, brs1, brs2);
  k_node_encode<<<node_blocks, 256, 0, stream>>>(x, n_enc_w, n_enc_b, n_ln_g, n_ln_b, h, h_bf);

  // agg zeroed once here; k_node_up2 re-zeroes it for the next layer
  hipMemsetAsync(agg, 0, (size_t)NN * H * 4, stream);
  for (int l = 0; l < NL; l++) {
    k_edge_mfma<<<edge_blocks, 256, 0, stream>>>(
        ea_bf, rsmu, src_s, dst_s, h_bf,
        bgh + (size_t)l * 65536, bm2 + (size_t)l * 16384,
        w2e + (size_t)l * 8192, msg_b2 + l * H, agg);
    k_node_up2<<<nup_blocks, 256, 0, stream>>>(
        agg, h_bf, h,
        brs1 + (size_t)l * 32768, brs2 + (size_t)l * 16384,
        res_b1 + l * H, res_b2 + l * H,
        ln_g + l * H, ln_b + l * H, h, h_bf);
  }

  hipMemsetAsync(gsum, 0, ((size_t)NG * H + NG) * 4, stream);
  k_pool<<<(NN + 31) / 32, 256, 0, stream>>>(h, batch, gsum, gcnt);
  k_readout<<<NG, 128, 0, stream>>>(gsum, gcnt, ro_w1, ro_b1, ro_w2, ro_b2, (float*)d_out);
}

// Round 7
// 938.050 us; speedup vs baseline: 1.5480x; 1.1332x over previous
//
#include <hip/hip_runtime.h>
#include <hip/hip_bf16.h>
#include <math.h>

#define NN 50000
#define NE 800000
#define NG 256
#define H 128
#define NIN 64
#define EIN 16
#define NL 3
#define LEPS 1e-5f

typedef short bf16x8 __attribute__((ext_vector_type(8)));
typedef float f32x4 __attribute__((ext_vector_type(4)));
typedef float f32x16 __attribute__((ext_vector_type(16)));
typedef unsigned u32x4 __attribute__((ext_vector_type(4)));

__device__ __forceinline__ short bf16rne(float x) {
  unsigned u = __float_as_uint(x);
  unsigned r = u + 0x7fff + ((u >> 16) & 1);
  return (short)(r >> 16);
}

// pack two floats to bf16 pair (lo in low short) — RNE, same bits as bf16rne
__device__ __forceinline__ unsigned pk2(float lo, float hi) {
  __hip_bfloat162 h = __float22bfloat162_rn(make_float2(lo, hi));
  return *(unsigned*)&h;
}

__device__ __forceinline__ float wsum(float v) {
#pragma unroll
  for (int m = 1; m < 64; m <<= 1) v += __shfl_xor(v, m, 64);
  return v;
}

// ---------------- sort-by-dst pipeline (once per launch) ----------------
__global__ __launch_bounds__(256) void k_count(const int* __restrict__ eidx,
                                               unsigned* __restrict__ cnt) {
  int t = blockIdx.x * 256 + threadIdx.x;
  if (t < NE) atomicAdd(&cnt[eidx[NE + t]], 1u);
}

__global__ __launch_bounds__(1024) void k_scan(const unsigned* __restrict__ cnt,
                                               unsigned* __restrict__ rowptr) {
  __shared__ unsigned part[16];
  __shared__ unsigned carry_s;
  const int tid = threadIdx.x, lane = tid & 63, wid = tid >> 6;
  if (tid == 0) carry_s = 0;
  __syncthreads();
  for (int base = 0; base < NN; base += 1024) {
    int i = base + tid;
    unsigned v = (i < NN) ? cnt[i] : 0u;
    unsigned incl = v;
#pragma unroll
    for (int off = 1; off < 64; off <<= 1) {
      unsigned t = __shfl_up(incl, off, 64);
      if (lane >= off) incl += t;
    }
    if (lane == 63) part[wid] = incl;
    __syncthreads();
    if (tid == 0) {
      unsigned s = 0;
#pragma unroll
      for (int w = 0; w < 16; w++) { unsigned t = part[w]; part[w] = s; s += t; }
    }
    __syncthreads();
    unsigned carry = carry_s;
    if (i < NN) rowptr[i] = carry + part[wid] + incl - v;
    __syncthreads();
    if (tid == 1023) carry_s = carry + part[15] + incl;
    __syncthreads();
  }
}

// ---------------- K_fold: LN-fold precompute (once) --------------------------
// W2e_ext[l]: 32 k-rows x 256 n, bf16, B-frag layout (verified R4/R5):
//   f = nt*2 + ks2 (f<16): k<16 : We·diag(g)·Wbot ; k=16: (be∘g)@Wbot ;
//   k=17: g@Wbot ; k=18: b_ln@Wbot + out-bias (gate_b | msg_b1) ; k>18: 0.
// stats: M[16][16]=We·We^T, wcs[16]=rowsum(We), v[16]=We@be, cc=Σbe², sbe=Σbe
__global__ __launch_bounds__(256) void k_fold(
    const float* __restrict__ gate_w, const float* __restrict__ msg_w1,
    const float* __restrict__ gate_b, const float* __restrict__ msg_b1,
    const float* __restrict__ e_enc_w, const float* __restrict__ e_enc_b,
    const float* __restrict__ e_ln_g, const float* __restrict__ e_ln_b,
    short* __restrict__ w2e, float* __restrict__ stats) {
  const int S_W2E = 3 * 8192;
  const int S_ST = S_W2E + 290;
  int tid = blockIdx.x * 256 + threadIdx.x;
  if (tid >= S_ST) return;
  if (tid < S_W2E) {
    int l = tid / 8192, e = tid % 8192;
    int f = e >> 9, lane = (e >> 3) & 63, j = e & 7;
    int nt = f >> 1, ks2 = f & 1;
    int k = ks2 * 16 + (lane >> 5) * 8 + j;
    int n = nt * 32 + (lane & 31);
    float s = 0.f;
    if (k < 19) {
      for (int m = 0; m < 128; m++) {
        float w = (n < 128) ? gate_w[((size_t)l * 256 + 128 + m) * 128 + n]
                            : msg_w1[((size_t)l * 256 + 128 + m) * 128 + (n - 128)];
        float fm = (k < 16)   ? e_enc_w[k * 128 + m] * e_ln_g[m]
                 : (k == 16)  ? e_enc_b[m] * e_ln_g[m]
                 : (k == 17)  ? e_ln_g[m]
                              : e_ln_b[m];
        s += fm * w;
      }
      if (k == 18)
        s += (n < 128) ? gate_b[l * 128 + n] : msg_b1[l * 128 + (n - 128)];
    }
    w2e[tid] = bf16rne(s);
  } else {
    int e = tid - S_W2E;
    if (e < 256) {
      int i = e >> 4, j = e & 15;
      float s = 0.f;
      for (int n = 0; n < 128; n++)
        s += e_enc_w[i * 128 + n] * e_enc_w[j * 128 + n];
      stats[e] = s;
    } else if (e < 272) {
      int k = e - 256;
      float s = 0.f;
      for (int n = 0; n < 128; n++) s += e_enc_w[k * 128 + n];
      stats[e] = s;
    } else if (e < 288) {
      int k = e - 272;
      float s = 0.f;
      for (int n = 0; n < 128; n++) s += e_enc_w[k * 128 + n] * e_enc_b[n];
      stats[e] = s;
    } else if (e == 288) {
      float s = 0.f;
      for (int n = 0; n < 128; n++) s += e_enc_b[n] * e_enc_b[n];
      stats[e] = s;
    } else {
      float s = 0.f;
      for (int n = 0; n < 128; n++) s += e_enc_b[n];
      stats[e] = s;
    }
  }
}

// ---------------- k_scatter: sort edges + bf16 ea + per-edge LN stats --------
__global__ __launch_bounds__(256) void k_scatter(
    const int* __restrict__ eidx, const float* __restrict__ ea,
    const unsigned* __restrict__ rowptr, unsigned* __restrict__ cursor,
    const float* __restrict__ stats,
    int* __restrict__ src_s, int* __restrict__ dst_s,
    short* __restrict__ ea_bf, float2* __restrict__ rsmu) {
  __shared__ float S[290];
  for (int i = threadIdx.x; i < 290; i += 256) S[i] = stats[i];
  __syncthreads();
  int t = blockIdx.x * 256 + threadIdx.x;
  int s = eidx[t], d = eidx[NE + t];
  unsigned pos = rowptr[d] + atomicAdd(&cursor[d], 1u);
  src_s[pos] = s;
  dst_s[pos] = d;
  const float4* er = (const float4*)(ea + (size_t)t * EIN);
  float4 q0 = er[0], q1 = er[1], q2 = er[2], q3 = er[3];
  float e16[16];
  e16[0]=q0.x; e16[1]=q0.y; e16[2]=q0.z; e16[3]=q0.w;
  e16[4]=q1.x; e16[5]=q1.y; e16[6]=q1.z; e16[7]=q1.w;
  e16[8]=q2.x; e16[9]=q2.y; e16[10]=q2.z; e16[11]=q2.w;
  e16[12]=q3.x; e16[13]=q3.y; e16[14]=q3.z; e16[15]=q3.w;
  short tmp[16];
#pragma unroll
  for (int j = 0; j < 16; j++) tmp[j] = bf16rne(e16[j]);
  short* dstp = ea_bf + (size_t)pos * EIN;
  *(bf16x8*)dstp = *(bf16x8*)tmp;
  *(bf16x8*)(dstp + 8) = *(bf16x8*)(tmp + 8);
  // LN stats (exact fp32)
  float s1 = S[289], s2 = S[288];
#pragma unroll
  for (int k = 0; k < 16; k++) {
    s1 = fmaf(e16[k], S[256 + k], s1);
    s2 = fmaf(2.f * e16[k], S[272 + k], s2);
  }
#pragma unroll
  for (int i = 0; i < 16; i++) {
    float mi = 0.f;
#pragma unroll
    for (int j = 0; j < 16; j++) mi = fmaf(S[i * 16 + j], e16[j], mi);
    s2 = fmaf(e16[i], mi, s2);
  }
  float mu = s1 * (1.f / 128.f);
  float var = s2 * (1.f / 128.f) - mu * mu;
  float rs = rsqrtf(var + LEPS);
  rsmu[pos] = make_float2(rs, mu);
}

// ---------------- K0: pre-swizzle weights -----------------------------------
__global__ __launch_bounds__(256) void k_convert_w(
    const float* __restrict__ gate_w, const float* __restrict__ msg_w1,
    const float* __restrict__ msg_w2, const float* __restrict__ res_w1,
    const float* __restrict__ res_w2,
    short* __restrict__ bgh, short* __restrict__ bm2,
    short* __restrict__ brs1, short* __restrict__ brs2) {
  const int S_BGH = 3 * 65536;
  const int S_BM2 = S_BGH + 3 * 16384;
  const int S_BR1 = S_BM2 + 3 * 32768;
  const int S_BR2 = S_BR1 + 3 * 16384;
  int tid = blockIdx.x * 256 + threadIdx.x;
  if (tid >= S_BR2) return;
  if (tid < S_BGH) {
    int l = tid / 65536, e = tid % 65536;
    int f = e >> 9, lane = (e >> 3) & 63, j = e & 7;
    int nt = f >> 4, ks = f & 15;
    int k = ks * 16 + (lane >> 5) * 8 + j;
    int n = nt * 32 + (lane & 31);
    float v = (n < 128) ? gate_w[((size_t)l * 256 + k) * 128 + n]
                        : msg_w1[((size_t)l * 256 + k) * 128 + (n - 128)];
    bgh[tid] = bf16rne(v);
  } else if (tid < S_BM2) {
    int e0 = tid - S_BGH;
    int l = e0 / 16384, e = e0 % 16384;
    int f = e >> 9, lane = (e >> 3) & 63, j = e & 7;
    int nt = f >> 3, ks = f & 7;
    int k = ks * 16 + (lane >> 5) * 8 + j;
    int n = nt * 32 + (lane & 31);
    bm2[e0] = bf16rne(msg_w2[((size_t)l * 128 + k) * 128 + n]);
  } else if (tid < S_BR1) {
    int e0 = tid - S_BM2;
    int l = e0 / 32768, e = e0 % 32768;
    int f = e >> 9, lane = (e >> 3) & 63, j = e & 7;
    int nt = f >> 3, ks = f & 7;
    int k = ks * 32 + (lane >> 4) * 8 + j;
    int n = nt * 16 + (lane & 15);
    brs1[e0] = bf16rne(res_w1[((size_t)l * 256 + k) * 128 + n]);
  } else {
    int e0 = tid - S_BR1;
    int l = e0 / 16384, e = e0 % 16384;
    int f = e >> 9, lane = (e >> 3) & 63, j = e & 7;
    int nt = f >> 2, ks = f & 3;
    int k = ks * 32 + (lane >> 4) * 8 + j;
    int n = nt * 16 + (lane & 15);
    brs2[e0] = bf16rne(res_w2[((size_t)l * 128 + k) * 128 + n]);
  }
}

// ---------------- K1: h = LN(x @ Wn + bn), also emit bf16 copy ----------------
__global__ __launch_bounds__(256) void k_node_encode(
    const float* __restrict__ x, const float* __restrict__ W,
    const float* __restrict__ bias,
    const float* __restrict__ lng, const float* __restrict__ lnb,
    float* __restrict__ h, short* __restrict__ h_bf) {
  __shared__ float xs[4][8 * NIN];
  const int wave = threadIdx.x >> 6, lane = threadIdx.x & 63;
  const int n0 = (blockIdx.x * 4 + wave) * 8;
  float* xt = xs[wave];
  for (int i = lane; i < 8 * NIN; i += 64) {
    int idx = n0 * NIN + i;
    xt[i] = (idx < NN * NIN) ? x[idx] : 0.f;
  }
  __syncthreads();
  const int c0 = lane, c1 = lane + 64;
  float a0[8], a1[8];
#pragma unroll
  for (int j = 0; j < 8; j++) { a0[j] = 0.f; a1[j] = 0.f; }
  for (int k = 0; k < NIN; k++) {
    float w0 = W[k * H + c0], w1 = W[k * H + c1];
#pragma unroll
    for (int j = 0; j < 8; j++) {
      float xv = xt[j * NIN + k];
      a0[j] = fmaf(xv, w0, a0[j]);
      a1[j] = fmaf(xv, w1, a1[j]);
    }
  }
  const float b0 = bias[c0], b1 = bias[c1];
  const float g0 = lng[c0], g1 = lng[c1], lb0 = lnb[c0], lb1 = lnb[c1];
#pragma unroll
  for (int j = 0; j < 8; j++) {
    float v0 = a0[j] + b0, v1 = a1[j] + b1;
    float mean = wsum(v0 + v1) * (1.f / H);
    float d0 = v0 - mean, d1 = v1 - mean;
    float var = wsum(d0 * d0 + d1 * d1) * (1.f / H);
    float rs = rsqrtf(var + LEPS);
    int n = n0 + j;
    if (n < NN) {
      float o0 = d0 * rs * g0 + lb0, o1 = d1 * rs * g1 + lb1;
      h[n * H + c0] = o0;
      h[n * H + c1] = o1;
      h_bf[n * H + c0] = bf16rne(o0);
      h_bf[n * H + c1] = bf16rne(o1);
    }
  }
}

// ---------------- K3: MFMA edge kernel, LDS-staged weights + R7 opts ---------
// R6 structure (M=32 edges/wave, dbuf LDS weight staging, K-row LN fold) plus:
//  (1) XCD-chunked bijective block swizzle: consecutive logical blocks (=
//      contiguous sorted-dst ranges) stay on one XCD so agg atomics hit a
//      ~3.2MB slice that fits the XCD-private 4MB L2 (no cross-XCD ping-pong).
//  (2) All 16 W2e frags preloaded to registers (removes chain-head L2 loads).
//  (3) s_setprio(1) around MFMA chains (waves desync around barriers/flush).
// Tile order: H4 H5 H6 H7 | G0 M0 G1 M1 G2 M2 G3 M3.
// C/D: col=lane&31, row=(reg&3)+8*(reg>>2)+4*(lane>>5).  A/B: m/n=lane&31,
// k=(lane>>5)*8+j.
__global__ __launch_bounds__(256) void k_edge_mfma(
    const short* __restrict__ ea_bf, const float2* __restrict__ rsmu,
    const int* __restrict__ src_s, const int* __restrict__ dst_s,
    const short* __restrict__ h_bf,
    const short* __restrict__ Bgh, const short* __restrict__ Bm2,
    const short* __restrict__ W2e, const float* __restrict__ mbias2,
    float* __restrict__ agg) {
  __shared__ short wbuf[2][4096];       // 8 frags/tile, dbuf: 16 KB
  __shared__ short regn[4][32 * 136];   // T2 + msg staging, 34.8 KB
  __shared__ int dsts[4][32];
  const int tid = threadIdx.x;
  const int wave = tid >> 6, lane = tid & 63;
  // (1) bijective XCD-chunk swizzle for nwg = 6250 = 8*781 + 2  (m204 form)
  const int xcd = blockIdx.x & 7, bidx = blockIdx.x >> 3;
  const int blk = (xcd < 2 ? xcd * 782 : 2 * 782 + (xcd - 2) * 781) + bidx;
  const int e0 = blk * 128 + wave * 32;
  short* R = regn[wave];
  float* Rf = (float*)R;                // float view: Rf[row*68 + c]
  const int c31 = lane & 31, halfl = lane >> 5;
  const int koff = halfl * 8;
  const int soff0 = (2 * wave) * 512 + lane * 8;      // this wave's 2 frag slots
  const int soff1 = (2 * wave + 1) * 512 + lane * 8;

  if (lane < 32) dsts[wave][lane] = dst_s[e0 + lane];

  // ---- (2) preload all 16 W2e fragments (64 VGPR) ----
  bf16x8 w2ef[16];
#pragma unroll
  for (int f = 0; f < 16; f++)
    w2ef[f] = *(const bf16x8*)(W2e + (size_t)(f * 64 + lane) * 8);

  // ---- A operands ----
  const int srow = src_s[e0 + c31];
  bf16x8 af[8];
#pragma unroll
  for (int ks = 0; ks < 8; ks++)
    af[ks] = *(const bf16x8*)(h_bf + (size_t)srow * H + ks * 16 + koff);

  const float2 rm = rsmu[e0 + c31];
  bf16x8 ae;
  {
    bf16x8 raw = *(const bf16x8*)(ea_bf + (size_t)(e0 + c31) * EIN + koff);
    u32x4 v;
#pragma unroll
    for (int p = 0; p < 4; p++) {
      float lo = __uint_as_float(((unsigned)(unsigned short)raw[2 * p]) << 16) * rm.x;
      float hi = __uint_as_float(((unsigned)(unsigned short)raw[2 * p + 1]) << 16) * rm.x;
      v[p] = pk2(lo, hi);
    }
    ae = __builtin_bit_cast(bf16x8, v);
  }
  bf16x8 ae2;
  {
    u32x4 w;
    w[0] = halfl ? 0u : pk2(rm.x, -rm.x * rm.y);   // k16=rs, k17=-rs*mu
    w[1] = halfl ? 0u : 0x00003F80u;               // k18=1.0
    w[2] = 0u; w[3] = 0u;
    ae2 = __builtin_bit_cast(bf16x8, w);
  }

  // ---- tile source bases (shorts): H4..H7, G0,M0,G1,M1,G2,M2,G3,M3 ----
  // H_i -> Bgh + (4+i)*8192 ; G_j -> Bgh + j*8192 ; M_j -> Bm2 + j*4096
  // prologue: stage tile 0 (H4)
  {
    const short* s = Bgh + (size_t)4 * 8192;
    bf16x8 p0 = *(const bf16x8*)(s + soff0);
    bf16x8 p1 = *(const bf16x8*)(s + soff1);
    *(bf16x8*)&wbuf[0][soff0] = p0;
    *(bf16x8*)&wbuf[0][soff1] = p1;
  }
  __syncthreads();

  bf16x8 a2[8];
  float gate[16];
  bf16x8 sl0, sl1;

#pragma unroll
  for (int t = 0; t < 12; t++) {
    const int b = t & 1;
    // ---- issue next tile's stage loads (held in regs until iteration end) --
    if (t < 11) {
      const int tn = t + 1;
      const short* s;
      if (tn < 4) s = Bgh + (size_t)(4 + tn) * 8192;
      else if (((tn - 4) & 1) == 0) s = Bgh + (size_t)((tn - 4) >> 1) * 8192;
      else s = Bm2 + (size_t)((tn - 4) >> 1) * 4096;
      sl0 = *(const bf16x8*)(s + soff0);
      sl1 = *(const bf16x8*)(s + soff1);
    }
    // ---- compute tile t from wbuf[b] ----
    if (t < 4) {                       // hidden nt = 4+t
      const int nt = 4 + t;
      __builtin_amdgcn_s_setprio(1);
      f32x16 a = __builtin_amdgcn_mfma_f32_32x32x16_bf16(
          ae, w2ef[nt * 2], (f32x16)(0.f), 0, 0, 0);
      a = __builtin_amdgcn_mfma_f32_32x32x16_bf16(ae2, w2ef[nt * 2 + 1], a, 0, 0, 0);
#pragma unroll
      for (int ks = 0; ks < 8; ks++)
        a = __builtin_amdgcn_mfma_f32_32x32x16_bf16(
            af[ks], *(const bf16x8*)&wbuf[b][ks * 512 + lane * 8], a, 0, 0, 0);
      __builtin_amdgcn_s_setprio(0);
      const int col = t * 32 + c31;
#pragma unroll
      for (int r = 0; r < 16; r++) {
        int row = (r & 3) + 8 * (r >> 2) + 4 * halfl;
        R[row * 136 + col] = bf16rne(fmaxf(a[r], 0.f));
      }
      if (t == 3) {                    // snapshot GEMM2 A-frags from T2
#pragma unroll
        for (int ks = 0; ks < 8; ks++)
          a2[ks] = *(const bf16x8*)&R[c31 * 136 + ks * 16 + koff];
      }
    } else if (((t - 4) & 1) == 0) {   // gate gt = (t-4)/2
      const int gt = (t - 4) >> 1;
      __builtin_amdgcn_s_setprio(1);
      f32x16 a = __builtin_amdgcn_mfma_f32_32x32x16_bf16(
          ae, w2ef[gt * 2], (f32x16)(0.f), 0, 0, 0);
      a = __builtin_amdgcn_mfma_f32_32x32x16_bf16(ae2, w2ef[gt * 2 + 1], a, 0, 0, 0);
#pragma unroll
      for (int ks = 0; ks < 8; ks++)
        a = __builtin_amdgcn_mfma_f32_32x32x16_bf16(
            af[ks], *(const bf16x8*)&wbuf[b][ks * 512 + lane * 8], a, 0, 0, 0);
      __builtin_amdgcn_s_setprio(0);
#pragma unroll
      for (int r = 0; r < 16; r++)
        gate[r] = __builtin_amdgcn_rcpf(1.f + __expf(-a[r]));
    } else {                           // msg gt = (t-4)/2
      const int gt = (t - 4) >> 1;
      const int t2 = gt & 1;
      __builtin_amdgcn_s_setprio(1);
      f32x16 m = (f32x16)(0.f);
#pragma unroll
      for (int ks = 0; ks < 8; ks++)
        m = __builtin_amdgcn_mfma_f32_32x32x16_bf16(
            a2[ks], *(const bf16x8*)&wbuf[b][ks * 512 + lane * 8], m, 0, 0, 0);
      __builtin_amdgcn_s_setprio(0);
      const float mb2 = mbias2[gt * 32 + c31];
      const int c2 = t2 * 32 + c31;
#pragma unroll
      for (int r = 0; r < 16; r++) {
        int row = (r & 3) + 8 * (r >> 2) + 4 * halfl;
        Rf[row * 68 + c2] = gate[r] * (m[r] + mb2);
      }
      if (t == 7 || t == 11) {
        // flush: lane owns column (hM*64 + lane); run-reduce 32 sorted rows
        const int hM = (t == 11);
        const int colg = hM * 64 + lane;
        int cur = dsts[wave][0];
        float run = Rf[lane];
#pragma unroll
        for (int row = 1; row < 32; row++) {
          int d = dsts[wave][row];
          float v = Rf[row * 68 + lane];
          if (d == cur) {
            run += v;
          } else {
            atomicAdd(&agg[(size_t)cur * H + colg], run);
            cur = d; run = v;
          }
        }
        atomicAdd(&agg[(size_t)cur * H + colg], run);
      }
    }
    // ---- stage write (barrier-protected, dbuf) ----
    if (t < 11) {
      __syncthreads();                 // all waves done reading wbuf[b^1] (t-1)
      *(bf16x8*)&wbuf[b ^ 1][soff0] = sl0;
      *(bf16x8*)&wbuf[b ^ 1][soff1] = sl1;
      __syncthreads();                 // tile t+1 data visible to all
    }
  }
}

// ---------------- K4: node update via MFMA (16x16x32, R3 exact) --------------
__global__ __launch_bounds__(256) void k_node_up2(
    float* agg, const short* __restrict__ h_bf_in,
    const float* __restrict__ h_in,
    const short* __restrict__ Brs1, const short* __restrict__ Brs2,
    const float* __restrict__ rb1, const float* __restrict__ rb2,
    const float* __restrict__ lng, const float* __restrict__ lnb,
    float* __restrict__ h, short* __restrict__ h_bf) {
  __shared__ short regn[4][16 * 136];
  const int tid = threadIdx.x;
  const int wave = tid >> 6, lane = tid & 63;
  const int n0 = blockIdx.x * 64 + wave * 16;
  short* R = regn[wave];
  const int mrow = lane & 15, quad = lane >> 4;

  int nr = n0 + mrow; if (nr >= NN) nr = NN - 1;
  bf16x8 af[8];
#pragma unroll
  for (int ks = 0; ks < 4; ks++)
    af[ks] = *(const bf16x8*)(h_bf_in + (size_t)nr * H + ks * 32 + quad * 8);
#pragma unroll
  for (int ks = 0; ks < 4; ks++) {
    float4 u = *(const float4*)(agg + (size_t)nr * H + ks * 32 + quad * 8);
    float4 w = *(const float4*)(agg + (size_t)nr * H + ks * 32 + quad * 8 + 4);
    short tmp[8];
    tmp[0]=bf16rne(u.x); tmp[1]=bf16rne(u.y); tmp[2]=bf16rne(u.z); tmp[3]=bf16rne(u.w);
    tmp[4]=bf16rne(w.x); tmp[5]=bf16rne(w.y); tmp[6]=bf16rne(w.z); tmp[7]=bf16rne(w.w);
    af[4 + ks] = *(bf16x8*)tmp;
  }
  float4 z4 = make_float4(0.f, 0.f, 0.f, 0.f);
#pragma unroll
  for (int ks = 0; ks < 4; ks++) {
    *(float4*)(agg + (size_t)nr * H + ks * 32 + quad * 8) = z4;
    *(float4*)(agg + (size_t)nr * H + ks * 32 + quad * 8 + 4) = z4;
  }

#pragma unroll
  for (int t = 0; t < 8; t++) {
    f32x4 a = (f32x4){0.f, 0.f, 0.f, 0.f};
#pragma unroll
    for (int ks = 0; ks < 8; ks++) {
      bf16x8 bf = *(const bf16x8*)(Brs1 + (size_t)((t * 8 + ks) * 64 + lane) * 8);
      a = __builtin_amdgcn_mfma_f32_16x16x32_bf16(af[ks], bf, a, 0, 0, 0);
    }
    int col = t * 16 + mrow;
    float b = rb1[col];
#pragma unroll
    for (int r = 0; r < 4; r++)
      R[(quad * 4 + r) * 136 + col] = bf16rne(fmaxf(a[r] + b, 0.f));
  }
  bf16x8 a2[4];
#pragma unroll
  for (int ks = 0; ks < 4; ks++)
    a2[ks] = *(const bf16x8*)&R[mrow * 136 + ks * 32 + quad * 8];

  float vals[8][4];
  float gl[8], bl[8];
#pragma unroll
  for (int t = 0; t < 8; t++) {
    f32x4 a = (f32x4){0.f, 0.f, 0.f, 0.f};
#pragma unroll
    for (int ks = 0; ks < 4; ks++) {
      bf16x8 bf = *(const bf16x8*)(Brs2 + (size_t)((t * 4 + ks) * 64 + lane) * 8);
      a = __builtin_amdgcn_mfma_f32_16x16x32_bf16(a2[ks], bf, a, 0, 0, 0);
    }
    int col = t * 16 + mrow;
    float b2 = rb2[col];
    gl[t] = lng[col]; bl[t] = lnb[col];
#pragma unroll
    for (int r = 0; r < 4; r++) {
      int rowi = n0 + quad * 4 + r;
      int rl = rowi < NN ? rowi : NN - 1;
      vals[t][r] = h_in[(size_t)rl * H + col] + a[r] + b2;
    }
  }
#pragma unroll
  for (int r = 0; r < 4; r++) {
    float s1 = 0.f, s2 = 0.f;
#pragma unroll
    for (int t = 0; t < 8; t++) {
      s1 += vals[t][r];
      s2 = fmaf(vals[t][r], vals[t][r], s2);
    }
#pragma unroll
    for (int m = 1; m < 16; m <<= 1) {
      s1 += __shfl_xor(s1, m, 64);
      s2 += __shfl_xor(s2, m, 64);
    }
    float mean = s1 * (1.f / 128.f);
    float var = s2 * (1.f / 128.f) - mean * mean;
    float rs = rsqrtf(var + LEPS);
    int rowi = n0 + quad * 4 + r;
    if (rowi < NN) {
#pragma unroll
      for (int t = 0; t < 8; t++) {
        int col = t * 16 + mrow;
        float o = (vals[t][r] - mean) * rs * gl[t] + bl[t];
        h[(size_t)rowi * H + col] = o;
        h_bf[(size_t)rowi * H + col] = bf16rne(o);
      }
    }
  }
}

// ---------------- K5: pooling, run-reduce over sorted batch ----------------
__global__ __launch_bounds__(256) void k_pool(
    const float* __restrict__ h, const int* __restrict__ batch,
    float* __restrict__ gsum, float* __restrict__ gcnt) {
  const int tid = threadIdx.x;
  const int col = tid & 127, half = tid >> 7;
  int n0 = blockIdx.x * 32 + half * 16;
  if (n0 >= NN) return;
  int end = n0 + 16; if (end > NN) end = NN;
  int cur = batch[n0];
  float run = h[(size_t)n0 * H + col];
  float cnt = 1.f;
  for (int n = n0 + 1; n < end; n++) {
    int b = batch[n];
    float v = h[(size_t)n * H + col];
    if (b == cur) { run += v; cnt += 1.f; }
    else {
      atomicAdd(&gsum[(size_t)cur * H + col], run);
      if (col == 0) atomicAdd(&gcnt[cur], cnt);
      cur = b; run = v; cnt = 1.f;
    }
  }
  atomicAdd(&gsum[(size_t)cur * H + col], run);
  if (col == 0) atomicAdd(&gcnt[cur], cnt);
}

// ---------------- K6: readout MLP ----------------
__global__ __launch_bounds__(128) void k_readout(
    const float* __restrict__ gsum, const float* __restrict__ gcnt,
    const float* __restrict__ W1, const float* __restrict__ b1,
    const float* __restrict__ W2, const float* __restrict__ b2,
    float* __restrict__ out) {
  __shared__ float gs[H];
  __shared__ float o1[H];
  int b = blockIdx.x, c = threadIdx.x;
  float cnt = fmaxf(gcnt[b], 1.f);
  gs[c] = gsum[b * H + c] / cnt;
  __syncthreads();
  float acc = b1[c];
  for (int k = 0; k < H; k++) acc = fmaf(gs[k], W1[k * H + c], acc);
  o1[c] = fmaxf(acc, 0.f);
  __syncthreads();
  if (c < 2) {
    float acc2 = b2[c];
    for (int k = 0; k < H; k++) acc2 = fmaf(o1[k], W2[k * 2 + c], acc2);
    out[b * 2 + c] = acc2;
  }
}

extern "C" void kernel_launch(void* const* d_in, const int* in_sizes, int n_in,
                              void* d_out, int out_size, void* d_ws, size_t ws_size,
                              hipStream_t stream) {
  (void)in_sizes; (void)n_in; (void)out_size; (void)ws_size;
  const float* x       = (const float*)d_in[0];
  const float* ea      = (const float*)d_in[1];
  const int*   eidx    = (const int*)d_in[2];
  const int*   batch   = (const int*)d_in[3];
  const float* n_enc_w = (const float*)d_in[4];
  const float* n_enc_b = (const float*)d_in[5];
  const float* e_enc_w = (const float*)d_in[6];
  const float* e_enc_b = (const float*)d_in[7];
  const float* n_ln_g  = (const float*)d_in[8];
  const float* n_ln_b  = (const float*)d_in[9];
  const float* e_ln_g  = (const float*)d_in[10];
  const float* e_ln_b  = (const float*)d_in[11];
  const float* msg_w1  = (const float*)d_in[12];
  const float* msg_b1  = (const float*)d_in[13];
  const float* msg_w2  = (const float*)d_in[14];
  const float* msg_b2  = (const float*)d_in[15];
  const float* gate_w  = (const float*)d_in[16];
  const float* gate_b  = (const float*)d_in[17];
  const float* res_w1  = (const float*)d_in[18];
  const float* res_b1  = (const float*)d_in[19];
  const float* res_w2  = (const float*)d_in[20];
  const float* res_b2  = (const float*)d_in[21];
  const float* ln_g    = (const float*)d_in[22];
  const float* ln_b    = (const float*)d_in[23];
  const float* ro_w1   = (const float*)d_in[24];
  const float* ro_b1   = (const float*)d_in[25];
  const float* ro_w2   = (const float*)d_in[26];
  const float* ro_b2   = (const float*)d_in[27];

  char* p = (char*)d_ws;
  float* h     = (float*)p;  p += (size_t)NN * H * 4;          // 25.6 MB
  short* h_bf  = (short*)p;  p += (size_t)NN * H * 2;          // 12.8 MB
  float* agg   = (float*)p;  p += (size_t)NN * H * 4;          // 25.6 MB
  short* ea_bf = (short*)p;  p += (size_t)NE * EIN * 2;        // 25.6 MB
  float2* rsmu = (float2*)p; p += (size_t)NE * 8;              // 6.4 MB
  float* gsum  = (float*)p;  p += (size_t)NG * H * 4;
  float* gcnt  = (float*)p;  p += 1024;
  short* bgh   = (short*)p;  p += (size_t)3 * 65536 * 2;
  short* bm2   = (short*)p;  p += (size_t)3 * 16384 * 2;
  short* brs1  = (short*)p;  p += (size_t)3 * 32768 * 2;
  short* brs2  = (short*)p;  p += (size_t)3 * 16384 * 2;
  short* w2e   = (short*)p;  p += (size_t)3 * 8192 * 2;
  float* stats = (float*)p;  p += 2048;
  unsigned* rowptr = (unsigned*)p; p += ((size_t)NN * 4 + 15) / 16 * 16;
  unsigned* cursor = (unsigned*)p; p += ((size_t)NN * 4 + 15) / 16 * 16;
  int* src_s   = (int*)p;    p += (size_t)NE * 4;
  int* dst_s   = (int*)p;    p += (size_t)NE * 4;
  // total ~103 MB (L3-resident working set)

  const int node_blocks = (NN + 31) / 32;
  const int nup_blocks  = (NN + 63) / 64;   // 782
  const int edge_blocks = NE / 128;         // 6250, exact
  const int e256 = (NE + 255) / 256;        // 3125, exact
  const int conv_total = 3 * 65536 + 3 * 16384 + 3 * 32768 + 3 * 16384;
  const int fold_total = 3 * 8192 + 290;

  hipMemsetAsync(cursor, 0, (size_t)NN * 4, stream);
  k_fold<<<(fold_total + 255) / 256, 256, 0, stream>>>(
      gate_w, msg_w1, gate_b, msg_b1, e_enc_w, e_enc_b, e_ln_g, e_ln_b,
      w2e, stats);
  k_count<<<e256, 256, 0, stream>>>(eidx, cursor);
  k_scan<<<1, 1024, 0, stream>>>(cursor, rowptr);
  hipMemsetAsync(cursor, 0, (size_t)NN * 4, stream);
  k_scatter<<<e256, 256, 0, stream>>>(eidx, ea, rowptr, cursor, stats,
                                      src_s, dst_s, ea_bf, rsmu);

  k_convert_w<<<(conv_total + 255) / 256, 256, 0, stream>>>(
      gate_w, msg_w1, msg_w2, res_w1, res_w2,
      bgh, bm2, brs1, brs2);
  k_node_encode<<<node_blocks, 256, 0, stream>>>(x, n_enc_w, n_enc_b, n_ln_g, n_ln_b, h, h_bf);

  // agg zeroed once here; k_node_up2 re-zeroes it for the next layer
  hipMemsetAsync(agg, 0, (size_t)NN * H * 4, stream);
  for (int l = 0; l < NL; l++) {
    k_edge_mfma<<<edge_blocks, 256, 0, stream>>>(
        ea_bf, rsmu, src_s, dst_s, h_bf,
        bgh + (size_t)l * 65536, bm2 + (size_t)l * 16384,
        w2e + (size_t)l * 8192, msg_b2 + l * H, agg);
    k_node_up2<<<nup_blocks, 256, 0, stream>>>(
        agg, h_bf, h,
        brs1 + (size_t)l * 32768, brs2 + (size_t)l * 16384,
        res_b1 + l * H, res_b2 + l * H,
        ln_g + l * H, ln_b + l * H, h, h_bf);
  }

  hipMemsetAsync(gsum, 0, ((size_t)NG * H + NG) * 4, stream);
  k_pool<<<(NN + 31) / 32, 256, 0, stream>>>(h, batch, gsum, gcnt);
  k_readout<<<NG, 128, 0, stream>>>(gsum, gcnt, ro_w1, ro_b1, ro_w2, ro_b2, (float*)d_out);
}

// Round 8
// 901.759 us; speedup vs baseline: 1.6103x; 1.0402x over previous
//
#include <hip/hip_runtime.h>
#include <hip/hip_bf16.h>
#include <math.h>

#define NN 50000
#define NE 800000
#define NG 256
#define H 128
#define NIN 64
#define EIN 16
#define NL 3
#define LEPS 1e-5f

typedef short bf16x8 __attribute__((ext_vector_type(8)));
typedef float f32x4 __attribute__((ext_vector_type(4)));
typedef float f32x16 __attribute__((ext_vector_type(16)));
typedef unsigned u32x4 __attribute__((ext_vector_type(4)));

__device__ __forceinline__ short bf16rne(float x) {
  unsigned u = __float_as_uint(x);
  unsigned r = u + 0x7fff + ((u >> 16) & 1);
  return (short)(r >> 16);
}

// pack two floats to bf16 pair (lo in low short) — RNE, same bits as bf16rne
__device__ __forceinline__ unsigned pk2(float lo, float hi) {
  __hip_bfloat162 h = __float22bfloat162_rn(make_float2(lo, hi));
  return *(unsigned*)&h;
}

__device__ __forceinline__ float wsum(float v) {
#pragma unroll
  for (int m = 1; m < 64; m <<= 1) v += __shfl_xor(v, m, 64);
  return v;
}

// ---------------- sort-by-dst pipeline (once per launch) ----------------
__global__ __launch_bounds__(256) void k_count(const int* __restrict__ eidx,
                                               unsigned* __restrict__ cnt) {
  int t = blockIdx.x * 256 + threadIdx.x;
  if (t < NE) atomicAdd(&cnt[eidx[NE + t]], 1u);
}

__global__ __launch_bounds__(1024) void k_scan(const unsigned* __restrict__ cnt,
                                               unsigned* __restrict__ rowptr) {
  __shared__ unsigned part[16];
  __shared__ unsigned carry_s;
  const int tid = threadIdx.x, lane = tid & 63, wid = tid >> 6;
  if (tid == 0) carry_s = 0;
  __syncthreads();
  for (int base = 0; base < NN; base += 1024) {
    int i = base + tid;
    unsigned v = (i < NN) ? cnt[i] : 0u;
    unsigned incl = v;
#pragma unroll
    for (int off = 1; off < 64; off <<= 1) {
      unsigned t = __shfl_up(incl, off, 64);
      if (lane >= off) incl += t;
    }
    if (lane == 63) part[wid] = incl;
    __syncthreads();
    if (tid == 0) {
      unsigned s = 0;
#pragma unroll
      for (int w = 0; w < 16; w++) { unsigned t = part[w]; part[w] = s; s += t; }
    }
    __syncthreads();
    unsigned carry = carry_s;
    if (i < NN) rowptr[i] = carry + part[wid] + incl - v;
    __syncthreads();
    if (tid == 1023) carry_s = carry + part[15] + incl;
    __syncthreads();
  }
}

// ---------------- K_fold: LN-fold precompute (once) --------------------------
// W2e_ext[l]: 32 k-rows x 256 n, bf16, B-frag layout (verified R4/R5):
//   f = nt*2 + ks2 (f<16): k<16 : We·diag(g)·Wbot ; k=16: (be∘g)@Wbot ;
//   k=17: g@Wbot ; k=18: b_ln@Wbot + out-bias (gate_b | msg_b1) ; k>18: 0.
// stats: M[16][16]=We·We^T, wcs[16]=rowsum(We), v[16]=We@be, cc=Σbe², sbe=Σbe
__global__ __launch_bounds__(256) void k_fold(
    const float* __restrict__ gate_w, const float* __restrict__ msg_w1,
    const float* __restrict__ gate_b, const float* __restrict__ msg_b1,
    const float* __restrict__ e_enc_w, const float* __restrict__ e_enc_b,
    const float* __restrict__ e_ln_g, const float* __restrict__ e_ln_b,
    short* __restrict__ w2e, float* __restrict__ stats) {
  const int S_W2E = 3 * 8192;
  const int S_ST = S_W2E + 290;
  int tid = blockIdx.x * 256 + threadIdx.x;
  if (tid >= S_ST) return;
  if (tid < S_W2E) {
    int l = tid / 8192, e = tid % 8192;
    int f = e >> 9, lane = (e >> 3) & 63, j = e & 7;
    int nt = f >> 1, ks2 = f & 1;
    int k = ks2 * 16 + (lane >> 5) * 8 + j;
    int n = nt * 32 + (lane & 31);
    float s = 0.f;
    if (k < 19) {
      for (int m = 0; m < 128; m++) {
        float w = (n < 128) ? gate_w[((size_t)l * 256 + 128 + m) * 128 + n]
                            : msg_w1[((size_t)l * 256 + 128 + m) * 128 + (n - 128)];
        float fm = (k < 16)   ? e_enc_w[k * 128 + m] * e_ln_g[m]
                 : (k == 16)  ? e_enc_b[m] * e_ln_g[m]
                 : (k == 17)  ? e_ln_g[m]
                              : e_ln_b[m];
        s += fm * w;
      }
      if (k == 18)
        s += (n < 128) ? gate_b[l * 128 + n] : msg_b1[l * 128 + (n - 128)];
    }
    w2e[tid] = bf16rne(s);
  } else {
    int e = tid - S_W2E;
    if (e < 256) {
      int i = e >> 4, j = e & 15;
      float s = 0.f;
      for (int n = 0; n < 128; n++)
        s += e_enc_w[i * 128 + n] * e_enc_w[j * 128 + n];
      stats[e] = s;
    } else if (e < 272) {
      int k = e - 256;
      float s = 0.f;
      for (int n = 0; n < 128; n++) s += e_enc_w[k * 128 + n];
      stats[e] = s;
    } else if (e < 288) {
      int k = e - 272;
      float s = 0.f;
      for (int n = 0; n < 128; n++) s += e_enc_w[k * 128 + n] * e_enc_b[n];
      stats[e] = s;
    } else if (e == 288) {
      float s = 0.f;
      for (int n = 0; n < 128; n++) s += e_enc_b[n] * e_enc_b[n];
      stats[e] = s;
    } else {
      float s = 0.f;
      for (int n = 0; n < 128; n++) s += e_enc_b[n];
      stats[e] = s;
    }
  }
}

// ---------------- k_scatter: sort edges + bf16 ea + per-edge LN stats --------
__global__ __launch_bounds__(256) void k_scatter(
    const int* __restrict__ eidx, const float* __restrict__ ea,
    const unsigned* __restrict__ rowptr, unsigned* __restrict__ cursor,
    const float* __restrict__ stats,
    int* __restrict__ src_s, int* __restrict__ dst_s,
    short* __restrict__ ea_bf, float2* __restrict__ rsmu) {
  __shared__ float S[290];
  for (int i = threadIdx.x; i < 290; i += 256) S[i] = stats[i];
  __syncthreads();
  int t = blockIdx.x * 256 + threadIdx.x;
  int s = eidx[t], d = eidx[NE + t];
  unsigned pos = rowptr[d] + atomicAdd(&cursor[d], 1u);
  src_s[pos] = s;
  dst_s[pos] = d;
  const float4* er = (const float4*)(ea + (size_t)t * EIN);
  float4 q0 = er[0], q1 = er[1], q2 = er[2], q3 = er[3];
  float e16[16];
  e16[0]=q0.x; e16[1]=q0.y; e16[2]=q0.z; e16[3]=q0.w;
  e16[4]=q1.x; e16[5]=q1.y; e16[6]=q1.z; e16[7]=q1.w;
  e16[8]=q2.x; e16[9]=q2.y; e16[10]=q2.z; e16[11]=q2.w;
  e16[12]=q3.x; e16[13]=q3.y; e16[14]=q3.z; e16[15]=q3.w;
  short tmp[16];
#pragma unroll
  for (int j = 0; j < 16; j++) tmp[j] = bf16rne(e16[j]);
  short* dstp = ea_bf + (size_t)pos * EIN;
  *(bf16x8*)dstp = *(bf16x8*)tmp;
  *(bf16x8*)(dstp + 8) = *(bf16x8*)(tmp + 8);
  // LN stats (exact fp32)
  float s1 = S[289], s2 = S[288];
#pragma unroll
  for (int k = 0; k < 16; k++) {
    s1 = fmaf(e16[k], S[256 + k], s1);
    s2 = fmaf(2.f * e16[k], S[272 + k], s2);
  }
#pragma unroll
  for (int i = 0; i < 16; i++) {
    float mi = 0.f;
#pragma unroll
    for (int j = 0; j < 16; j++) mi = fmaf(S[i * 16 + j], e16[j], mi);
    s2 = fmaf(e16[i], mi, s2);
  }
  float mu = s1 * (1.f / 128.f);
  float var = s2 * (1.f / 128.f) - mu * mu;
  float rs = rsqrtf(var + LEPS);
  rsmu[pos] = make_float2(rs, mu);
}

// ---------------- K0: pre-swizzle weights -----------------------------------
__global__ __launch_bounds__(256) void k_convert_w(
    const float* __restrict__ gate_w, const float* __restrict__ msg_w1,
    const float* __restrict__ msg_w2, const float* __restrict__ res_w1,
    const float* __restrict__ res_w2,
    short* __restrict__ bgh, short* __restrict__ bm2,
    short* __restrict__ brs1, short* __restrict__ brs2) {
  const int S_BGH = 3 * 65536;
  const int S_BM2 = S_BGH + 3 * 16384;
  const int S_BR1 = S_BM2 + 3 * 32768;
  const int S_BR2 = S_BR1 + 3 * 16384;
  int tid = blockIdx.x * 256 + threadIdx.x;
  if (tid >= S_BR2) return;
  if (tid < S_BGH) {
    int l = tid / 65536, e = tid % 65536;
    int f = e >> 9, lane = (e >> 3) & 63, j = e & 7;
    int nt = f >> 4, ks = f & 15;
    int k = ks * 16 + (lane >> 5) * 8 + j;
    int n = nt * 32 + (lane & 31);
    float v = (n < 128) ? gate_w[((size_t)l * 256 + k) * 128 + n]
                        : msg_w1[((size_t)l * 256 + k) * 128 + (n - 128)];
    bgh[tid] = bf16rne(v);
  } else if (tid < S_BM2) {
    int e0 = tid - S_BGH;
    int l = e0 / 16384, e = e0 % 16384;
    int f = e >> 9, lane = (e >> 3) & 63, j = e & 7;
    int nt = f >> 3, ks = f & 7;
    int k = ks * 16 + (lane >> 5) * 8 + j;
    int n = nt * 32 + (lane & 31);
    bm2[e0] = bf16rne(msg_w2[((size_t)l * 128 + k) * 128 + n]);
  } else if (tid < S_BR1) {
    int e0 = tid - S_BM2;
    int l = e0 / 32768, e = e0 % 32768;
    int f = e >> 9, lane = (e >> 3) & 63, j = e & 7;
    int nt = f >> 3, ks = f & 7;
    int k = ks * 32 + (lane >> 4) * 8 + j;
    int n = nt * 16 + (lane & 15);
    brs1[e0] = bf16rne(res_w1[((size_t)l * 256 + k) * 128 + n]);
  } else {
    int e0 = tid - S_BR1;
    int l = e0 / 16384, e = e0 % 16384;
    int f = e >> 9, lane = (e >> 3) & 63, j = e & 7;
    int nt = f >> 2, ks = f & 3;
    int k = ks * 32 + (lane >> 4) * 8 + j;
    int n = nt * 16 + (lane & 15);
    brs2[e0] = bf16rne(res_w2[((size_t)l * 128 + k) * 128 + n]);
  }
}

// ---------------- K1: h = LN(x @ Wn + bn), also emit bf16 copy ----------------
__global__ __launch_bounds__(256) void k_node_encode(
    const float* __restrict__ x, const float* __restrict__ W,
    const float* __restrict__ bias,
    const float* __restrict__ lng, const float* __restrict__ lnb,
    float* __restrict__ h, short* __restrict__ h_bf) {
  __shared__ float xs[4][8 * NIN];
  const int wave = threadIdx.x >> 6, lane = threadIdx.x & 63;
  const int n0 = (blockIdx.x * 4 + wave) * 8;
  float* xt = xs[wave];
  for (int i = lane; i < 8 * NIN; i += 64) {
    int idx = n0 * NIN + i;
    xt[i] = (idx < NN * NIN) ? x[idx] : 0.f;
  }
  __syncthreads();
  const int c0 = lane, c1 = lane + 64;
  float a0[8], a1[8];
#pragma unroll
  for (int j = 0; j < 8; j++) { a0[j] = 0.f; a1[j] = 0.f; }
  for (int k = 0; k < NIN; k++) {
    float w0 = W[k * H + c0], w1 = W[k * H + c1];
#pragma unroll
    for (int j = 0; j < 8; j++) {
      float xv = xt[j * NIN + k];
      a0[j] = fmaf(xv, w0, a0[j]);
      a1[j] = fmaf(xv, w1, a1[j]);
    }
  }
  const float b0 = bias[c0], b1 = bias[c1];
  const float g0 = lng[c0], g1 = lng[c1], lb0 = lnb[c0], lb1 = lnb[c1];
#pragma unroll
  for (int j = 0; j < 8; j++) {
    float v0 = a0[j] + b0, v1 = a1[j] + b1;
    float mean = wsum(v0 + v1) * (1.f / H);
    float d0 = v0 - mean, d1 = v1 - mean;
    float var = wsum(d0 * d0 + d1 * d1) * (1.f / H);
    float rs = rsqrtf(var + LEPS);
    int n = n0 + j;
    if (n < NN) {
      float o0 = d0 * rs * g0 + lb0, o1 = d1 * rs * g1 + lb1;
      h[n * H + c0] = o0;
      h[n * H + c1] = o1;
      h_bf[n * H + c0] = bf16rne(o0);
      h_bf[n * H + c1] = bf16rne(o1);
    }
  }
}

// ---------------- K3: MFMA edge kernel, LDS-staged weights + R8 opts ---------
// R7 structure plus:
//  (1) SINGLE barrier per tile (23 -> 12): with the double buffer, the barrier
//      at end of tile t-1 already guarantees all readers of wbuf[b^1] (tile
//      t-1's buffer) are done before tile t writes it.
//  (2) mbias2 hoisted to registers (no dependent global load in msg epilogue).
// Carried from R7: XCD-chunked bijective block swizzle (agg atomics stay in
// the XCD-private L2), all 16 W2e frags preloaded, setprio around MFMA chains.
// Tile order: H4 H5 H6 H7 | G0 M0 G1 M1 G2 M2 G3 M3.
// C/D: col=lane&31, row=(reg&3)+8*(reg>>2)+4*(lane>>5).  A/B: m/n=lane&31,
// k=(lane>>5)*8+j.
__global__ __launch_bounds__(256) void k_edge_mfma(
    const short* __restrict__ ea_bf, const float2* __restrict__ rsmu,
    const int* __restrict__ src_s, const int* __restrict__ dst_s,
    const short* __restrict__ h_bf,
    const short* __restrict__ Bgh, const short* __restrict__ Bm2,
    const short* __restrict__ W2e, const float* __restrict__ mbias2,
    float* __restrict__ agg) {
  __shared__ short wbuf[2][4096];       // 8 frags/tile, dbuf: 16 KB
  __shared__ short regn[4][32 * 136];   // T2 + msg staging, 34.8 KB
  __shared__ int dsts[4][32];
  const int tid = threadIdx.x;
  const int wave = tid >> 6, lane = tid & 63;
  // bijective XCD-chunk swizzle for nwg = 6250 = 8*781 + 2  (m204 form)
  const int xcd = blockIdx.x & 7, bidx = blockIdx.x >> 3;
  const int blk = (xcd < 2 ? xcd * 782 : 2 * 782 + (xcd - 2) * 781) + bidx;
  const int e0 = blk * 128 + wave * 32;
  short* R = regn[wave];
  float* Rf = (float*)R;                // float view: Rf[row*68 + c]
  const int c31 = lane & 31, halfl = lane >> 5;
  const int koff = halfl * 8;
  const int soff0 = (2 * wave) * 512 + lane * 8;      // this wave's 2 frag slots
  const int soff1 = (2 * wave + 1) * 512 + lane * 8;

  if (lane < 32) dsts[wave][lane] = dst_s[e0 + lane];

  // ---- preload all 16 W2e fragments (64 VGPR) + mbias2 ----
  bf16x8 w2ef[16];
#pragma unroll
  for (int f = 0; f < 16; f++)
    w2ef[f] = *(const bf16x8*)(W2e + (size_t)(f * 64 + lane) * 8);
  float mb2v[4];
#pragma unroll
  for (int gt = 0; gt < 4; gt++) mb2v[gt] = mbias2[gt * 32 + c31];

  // ---- A operands ----
  const int srow = src_s[e0 + c31];
  bf16x8 af[8];
#pragma unroll
  for (int ks = 0; ks < 8; ks++)
    af[ks] = *(const bf16x8*)(h_bf + (size_t)srow * H + ks * 16 + koff);

  const float2 rm = rsmu[e0 + c31];
  bf16x8 ae;
  {
    bf16x8 raw = *(const bf16x8*)(ea_bf + (size_t)(e0 + c31) * EIN + koff);
    u32x4 v;
#pragma unroll
    for (int p = 0; p < 4; p++) {
      float lo = __uint_as_float(((unsigned)(unsigned short)raw[2 * p]) << 16) * rm.x;
      float hi = __uint_as_float(((unsigned)(unsigned short)raw[2 * p + 1]) << 16) * rm.x;
      v[p] = pk2(lo, hi);
    }
    ae = __builtin_bit_cast(bf16x8, v);
  }
  bf16x8 ae2;
  {
    u32x4 w;
    w[0] = halfl ? 0u : pk2(rm.x, -rm.x * rm.y);   // k16=rs, k17=-rs*mu
    w[1] = halfl ? 0u : 0x00003F80u;               // k18=1.0
    w[2] = 0u; w[3] = 0u;
    ae2 = __builtin_bit_cast(bf16x8, w);
  }

  // ---- tile source bases (shorts): H4..H7, G0,M0,G1,M1,G2,M2,G3,M3 ----
  // H_i -> Bgh + (4+i)*8192 ; G_j -> Bgh + j*8192 ; M_j -> Bm2 + j*4096
  // prologue: stage tile 0 (H4)
  {
    const short* s = Bgh + (size_t)4 * 8192;
    bf16x8 p0 = *(const bf16x8*)(s + soff0);
    bf16x8 p1 = *(const bf16x8*)(s + soff1);
    *(bf16x8*)&wbuf[0][soff0] = p0;
    *(bf16x8*)&wbuf[0][soff1] = p1;
  }
  __syncthreads();

  bf16x8 a2[8];
  float gate[16];
  bf16x8 sl0, sl1;

#pragma unroll
  for (int t = 0; t < 12; t++) {
    const int b = t & 1;
    // ---- issue next tile's stage loads (held in regs until iteration end) --
    if (t < 11) {
      const int tn = t + 1;
      const short* s;
      if (tn < 4) s = Bgh + (size_t)(4 + tn) * 8192;
      else if (((tn - 4) & 1) == 0) s = Bgh + (size_t)((tn - 4) >> 1) * 8192;
      else s = Bm2 + (size_t)((tn - 4) >> 1) * 4096;
      sl0 = *(const bf16x8*)(s + soff0);
      sl1 = *(const bf16x8*)(s + soff1);
    }
    // ---- compute tile t from wbuf[b] ----
    if (t < 4) {                       // hidden nt = 4+t
      const int nt = 4 + t;
      __builtin_amdgcn_s_setprio(1);
      f32x16 a = __builtin_amdgcn_mfma_f32_32x32x16_bf16(
          ae, w2ef[nt * 2], (f32x16)(0.f), 0, 0, 0);
      a = __builtin_amdgcn_mfma_f32_32x32x16_bf16(ae2, w2ef[nt * 2 + 1], a, 0, 0, 0);
#pragma unroll
      for (int ks = 0; ks < 8; ks++)
        a = __builtin_amdgcn_mfma_f32_32x32x16_bf16(
            af[ks], *(const bf16x8*)&wbuf[b][ks * 512 + lane * 8], a, 0, 0, 0);
      __builtin_amdgcn_s_setprio(0);
      const int col = t * 32 + c31;
#pragma unroll
      for (int r = 0; r < 16; r++) {
        int row = (r & 3) + 8 * (r >> 2) + 4 * halfl;
        R[row * 136 + col] = bf16rne(fmaxf(a[r], 0.f));
      }
      if (t == 3) {                    // snapshot GEMM2 A-frags from T2
#pragma unroll
        for (int ks = 0; ks < 8; ks++)
          a2[ks] = *(const bf16x8*)&R[c31 * 136 + ks * 16 + koff];
      }
    } else if (((t - 4) & 1) == 0) {   // gate gt = (t-4)/2
      const int gt = (t - 4) >> 1;
      __builtin_amdgcn_s_setprio(1);
      f32x16 a = __builtin_amdgcn_mfma_f32_32x32x16_bf16(
          ae, w2ef[gt * 2], (f32x16)(0.f), 0, 0, 0);
      a = __builtin_amdgcn_mfma_f32_32x32x16_bf16(ae2, w2ef[gt * 2 + 1], a, 0, 0, 0);
#pragma unroll
      for (int ks = 0; ks < 8; ks++)
        a = __builtin_amdgcn_mfma_f32_32x32x16_bf16(
            af[ks], *(const bf16x8*)&wbuf[b][ks * 512 + lane * 8], a, 0, 0, 0);
      __builtin_amdgcn_s_setprio(0);
#pragma unroll
      for (int r = 0; r < 16; r++)
        gate[r] = __builtin_amdgcn_rcpf(1.f + __expf(-a[r]));
    } else {                           // msg gt = (t-4)/2
      const int gt = (t - 4) >> 1;
      const int t2 = gt & 1;
      __builtin_amdgcn_s_setprio(1);
      f32x16 m = (f32x16)(0.f);
#pragma unroll
      for (int ks = 0; ks < 8; ks++)
        m = __builtin_amdgcn_mfma_f32_32x32x16_bf16(
            a2[ks], *(const bf16x8*)&wbuf[b][ks * 512 + lane * 8], m, 0, 0, 0);
      __builtin_amdgcn_s_setprio(0);
      const float mb2 = mb2v[gt];
      const int c2 = t2 * 32 + c31;
#pragma unroll
      for (int r = 0; r < 16; r++) {
        int row = (r & 3) + 8 * (r >> 2) + 4 * halfl;
        Rf[row * 68 + c2] = gate[r] * (m[r] + mb2);
      }
      if (t == 7 || t == 11) {
        // flush: lane owns column (hM*64 + lane); run-reduce 32 sorted rows
        const int hM = (t == 11);
        const int colg = hM * 64 + lane;
        int cur = dsts[wave][0];
        float run = Rf[lane];
#pragma unroll
        for (int row = 1; row < 32; row++) {
          int d = dsts[wave][row];
          float v = Rf[row * 68 + lane];
          if (d == cur) {
            run += v;
          } else {
            atomicAdd(&agg[(size_t)cur * H + colg], run);
            cur = d; run = v;
          }
        }
        atomicAdd(&agg[(size_t)cur * H + colg], run);
      }
    }
    // ---- stage write: SINGLE barrier per tile (safety: the barrier at end
    // of tile t-1 means all readers of wbuf[b^1] (= tile t-1's buffer) are
    // done before this write) ----
    if (t < 11) {
      *(bf16x8*)&wbuf[b ^ 1][soff0] = sl0;
      *(bf16x8*)&wbuf[b ^ 1][soff1] = sl1;
      __syncthreads();
    }
  }
}

// ---------------- K4: node update via MFMA (16x16x32) ------------------------
// R8: XCD-chunked bijective swizzle (nwg=782=8*97+6) aligned with the edge
// kernel's agg-producer chunking — agg reads/zeroes stay in the same XCD L2.
__global__ __launch_bounds__(256) void k_node_up2(
    float* agg, const short* __restrict__ h_bf_in,
    const float* __restrict__ h_in,
    const short* __restrict__ Brs1, const short* __restrict__ Brs2,
    const float* __restrict__ rb1, const float* __restrict__ rb2,
    const float* __restrict__ lng, const float* __restrict__ lnb,
    float* __restrict__ h, short* __restrict__ h_bf) {
  __shared__ short regn[4][16 * 136];
  const int tid = threadIdx.x;
  const int wave = tid >> 6, lane = tid & 63;
  const int xcd = blockIdx.x & 7, bidx = blockIdx.x >> 3;   // nwg=782: q=97,r=6
  const int blk = (xcd < 6 ? xcd * 98 : 6 * 98 + (xcd - 6) * 97) + bidx;
  const int n0 = blk * 64 + wave * 16;
  short* R = regn[wave];
  const int mrow = lane & 15, quad = lane >> 4;

  int nr = n0 + mrow; if (nr >= NN) nr = NN - 1;
  bf16x8 af[8];
#pragma unroll
  for (int ks = 0; ks < 4; ks++)
    af[ks] = *(const bf16x8*)(h_bf_in + (size_t)nr * H + ks * 32 + quad * 8);
#pragma unroll
  for (int ks = 0; ks < 4; ks++) {
    float4 u = *(const float4*)(agg + (size_t)nr * H + ks * 32 + quad * 8);
    float4 w = *(const float4*)(agg + (size_t)nr * H + ks * 32 + quad * 8 + 4);
    short tmp[8];
    tmp[0]=bf16rne(u.x); tmp[1]=bf16rne(u.y); tmp[2]=bf16rne(u.z); tmp[3]=bf16rne(u.w);
    tmp[4]=bf16rne(w.x); tmp[5]=bf16rne(w.y); tmp[6]=bf16rne(w.z); tmp[7]=bf16rne(w.w);
    af[4 + ks] = *(bf16x8*)tmp;
  }
  float4 z4 = make_float4(0.f, 0.f, 0.f, 0.f);
#pragma unroll
  for (int ks = 0; ks < 4; ks++) {
    *(float4*)(agg + (size_t)nr * H + ks * 32 + quad * 8) = z4;
    *(float4*)(agg + (size_t)nr * H + ks * 32 + quad * 8 + 4) = z4;
  }

#pragma unroll
  for (int t = 0; t < 8; t++) {
    f32x4 a = (f32x4){0.f, 0.f, 0.f, 0.f};
#pragma unroll
    for (int ks = 0; ks < 8; ks++) {
      bf16x8 bf = *(const bf16x8*)(Brs1 + (size_t)((t * 8 + ks) * 64 + lane) * 8);
      a = __builtin_amdgcn_mfma_f32_16x16x32_bf16(af[ks], bf, a, 0, 0, 0);
    }
    int col = t * 16 + mrow;
    float b = rb1[col];
#pragma unroll
    for (int r = 0; r < 4; r++)
      R[(quad * 4 + r) * 136 + col] = bf16rne(fmaxf(a[r] + b, 0.f));
  }
  bf16x8 a2[4];
#pragma unroll
  for (int ks = 0; ks < 4; ks++)
    a2[ks] = *(const bf16x8*)&R[mrow * 136 + ks * 32 + quad * 8];

  float vals[8][4];
  float gl[8], bl[8];
#pragma unroll
  for (int t = 0; t < 8; t++) {
    f32x4 a = (f32x4){0.f, 0.f, 0.f, 0.f};
#pragma unroll
    for (int ks = 0; ks < 4; ks++) {
      bf16x8 bf = *(const bf16x8*)(Brs2 + (size_t)((t * 4 + ks) * 64 + lane) * 8);
      a = __builtin_amdgcn_mfma_f32_16x16x32_bf16(a2[ks], bf, a, 0, 0, 0);
    }
    int col = t * 16 + mrow;
    float b2 = rb2[col];
    gl[t] = lng[col]; bl[t] = lnb[col];
#pragma unroll
    for (int r = 0; r < 4; r++) {
      int rowi = n0 + quad * 4 + r;
      int rl = rowi < NN ? rowi : NN - 1;
      vals[t][r] = h_in[(size_t)rl * H + col] + a[r] + b2;
    }
  }
#pragma unroll
  for (int r = 0; r < 4; r++) {
    float s1 = 0.f, s2 = 0.f;
#pragma unroll
    for (int t = 0; t < 8; t++) {
      s1 += vals[t][r];
      s2 = fmaf(vals[t][r], vals[t][r], s2);
    }
#pragma unroll
    for (int m = 1; m < 16; m <<= 1) {
      s1 += __shfl_xor(s1, m, 64);
      s2 += __shfl_xor(s2, m, 64);
    }
    float mean = s1 * (1.f / 128.f);
    float var = s2 * (1.f / 128.f) - mean * mean;
    float rs = rsqrtf(var + LEPS);
    int rowi = n0 + quad * 4 + r;
    if (rowi < NN) {
#pragma unroll
      for (int t = 0; t < 8; t++) {
        int col = t * 16 + mrow;
        float o = (vals[t][r] - mean) * rs * gl[t] + bl[t];
        h[(size_t)rowi * H + col] = o;
        h_bf[(size_t)rowi * H + col] = bf16rne(o);
      }
    }
  }
}

// ---------------- K5: pooling, run-reduce over sorted batch ----------------
// R8: XCD-aligned swizzle (nwg=1563=8*195+3) so h reads hit the producing
// XCD's L2.
__global__ __launch_bounds__(256) void k_pool(
    const float* __restrict__ h, const int* __restrict__ batch,
    float* __restrict__ gsum, float* __restrict__ gcnt) {
  const int tid = threadIdx.x;
  const int col = tid & 127, half = tid >> 7;
  const int xcd = blockIdx.x & 7, bidx = blockIdx.x >> 3;  // q=195, r=3
  const int blk = (xcd < 3 ? xcd * 196 : 3 * 196 + (xcd - 3) * 195) + bidx;
  int n0 = blk * 32 + half * 16;
  if (n0 >= NN) return;
  int end = n0 + 16; if (end > NN) end = NN;
  int cur = batch[n0];
  float run = h[(size_t)n0 * H + col];
  float cnt = 1.f;
  for (int n = n0 + 1; n < end; n++) {
    int b = batch[n];
    float v = h[(size_t)n * H + col];
    if (b == cur) { run += v; cnt += 1.f; }
    else {
      atomicAdd(&gsum[(size_t)cur * H + col], run);
      if (col == 0) atomicAdd(&gcnt[cur], cnt);
      cur = b; run = v; cnt = 1.f;
    }
  }
  atomicAdd(&gsum[(size_t)cur * H + col], run);
  if (col == 0) atomicAdd(&gcnt[cur], cnt);
}

// ---------------- K6: readout MLP ----------------
__global__ __launch_bounds__(128) void k_readout(
    const float* __restrict__ gsum, const float* __restrict__ gcnt,
    const float* __restrict__ W1, const float* __restrict__ b1,
    const float* __restrict__ W2, const float* __restrict__ b2,
    float* __restrict__ out) {
  __shared__ float gs[H];
  __shared__ float o1[H];
  int b = blockIdx.x, c = threadIdx.x;
  float cnt = fmaxf(gcnt[b], 1.f);
  gs[c] = gsum[b * H + c] / cnt;
  __syncthreads();
  float acc = b1[c];
  for (int k = 0; k < H; k++) acc = fmaf(gs[k], W1[k * H + c], acc);
  o1[c] = fmaxf(acc, 0.f);
  __syncthreads();
  if (c < 2) {
    float acc2 = b2[c];
    for (int k = 0; k < H; k++) acc2 = fmaf(o1[k], W2[k * 2 + c], acc2);
    out[b * 2 + c] = acc2;
  }
}

extern "C" void kernel_launch(void* const* d_in, const int* in_sizes, int n_in,
                              void* d_out, int out_size, void* d_ws, size_t ws_size,
                              hipStream_t stream) {
  (void)in_sizes; (void)n_in; (void)out_size; (void)ws_size;
  const float* x       = (const float*)d_in[0];
  const float* ea      = (const float*)d_in[1];
  const int*   eidx    = (const int*)d_in[2];
  const int*   batch   = (const int*)d_in[3];
  const float* n_enc_w = (const float*)d_in[4];
  const float* n_enc_b = (const float*)d_in[5];
  const float* e_enc_w = (const float*)d_in[6];
  const float* e_enc_b = (const float*)d_in[7];
  const float* n_ln_g  = (const float*)d_in[8];
  const float* n_ln_b  = (const float*)d_in[9];
  const float* e_ln_g  = (const float*)d_in[10];
  const float* e_ln_b  = (const float*)d_in[11];
  const float* msg_w1  = (const float*)d_in[12];
  const float* msg_b1  = (const float*)d_in[13];
  const float* msg_w2  = (const float*)d_in[14];
  const float* msg_b2  = (const float*)d_in[15];
  const float* gate_w  = (const float*)d_in[16];
  const float* gate_b  = (const float*)d_in[17];
  const float* res_w1  = (const float*)d_in[18];
  const float* res_b1  = (const float*)d_in[19];
  const float* res_w2  = (const float*)d_in[20];
  const float* res_b2  = (const float*)d_in[21];
  const float* ln_g    = (const float*)d_in[22];
  const float* ln_b    = (const float*)d_in[23];
  const float* ro_w1   = (const float*)d_in[24];
  const float* ro_b1   = (const float*)d_in[25];
  const float* ro_w2   = (const float*)d_in[26];
  const float* ro_b2   = (const float*)d_in[27];

  char* p = (char*)d_ws;
  float* h     = (float*)p;  p += (size_t)NN * H * 4;          // 25.6 MB
  short* h_bf  = (short*)p;  p += (size_t)NN * H * 2;          // 12.8 MB
  float* agg   = (float*)p;  p += (size_t)NN * H * 4;          // 25.6 MB
  short* ea_bf = (short*)p;  p += (size_t)NE * EIN * 2;        // 25.6 MB
  float2* rsmu = (float2*)p; p += (size_t)NE * 8;              // 6.4 MB
  float* gsum  = (float*)p;  p += (size_t)NG * H * 4;
  float* gcnt  = (float*)p;  p += 1024;
  short* bgh   = (short*)p;  p += (size_t)3 * 65536 * 2;
  short* bm2   = (short*)p;  p += (size_t)3 * 16384 * 2;
  short* brs1  = (short*)p;  p += (size_t)3 * 32768 * 2;
  short* brs2  = (short*)p;  p += (size_t)3 * 16384 * 2;
  short* w2e   = (short*)p;  p += (size_t)3 * 8192 * 2;
  float* stats = (float*)p;  p += 2048;
  unsigned* rowptr = (unsigned*)p; p += ((size_t)NN * 4 + 15) / 16 * 16;
  unsigned* cursor = (unsigned*)p; p += ((size_t)NN * 4 + 15) / 16 * 16;
  int* src_s   = (int*)p;    p += (size_t)NE * 4;
  int* dst_s   = (int*)p;    p += (size_t)NE * 4;
  // total ~103 MB (L3-resident working set)

  const int node_blocks = (NN + 31) / 32;
  const int nup_blocks  = (NN + 63) / 64;   // 782
  const int edge_blocks = NE / 128;         // 6250, exact
  const int e256 = (NE + 255) / 256;        // 3125, exact
  const int conv_total = 3 * 65536 + 3 * 16384 + 3 * 32768 + 3 * 16384;
  const int fold_total = 3 * 8192 + 290;

  hipMemsetAsync(cursor, 0, (size_t)NN * 4, stream);
  k_fold<<<(fold_total + 255) / 256, 256, 0, stream>>>(
      gate_w, msg_w1, gate_b, msg_b1, e_enc_w, e_enc_b, e_ln_g, e_ln_b,
      w2e, stats);
  k_count<<<e256, 256, 0, stream>>>(eidx, cursor);
  k_scan<<<1, 1024, 0, stream>>>(cursor, rowptr);
  hipMemsetAsync(cursor, 0, (size_t)NN * 4, stream);
  k_scatter<<<e256, 256, 0, stream>>>(eidx, ea, rowptr, cursor, stats,
                                      src_s, dst_s, ea_bf, rsmu);

  k_convert_w<<<(conv_total + 255) / 256, 256, 0, stream>>>(
      gate_w, msg_w1, msg_w2, res_w1, res_w2,
      bgh, bm2, brs1, brs2);
  k_node_encode<<<node_blocks, 256, 0, stream>>>(x, n_enc_w, n_enc_b, n_ln_g, n_ln_b, h, h_bf);

  // agg zeroed once here; k_node_up2 re-zeroes it for the next layer
  hipMemsetAsync(agg, 0, (size_t)NN * H * 4, stream);
  for (int l = 0; l < NL; l++) {
    k_edge_mfma<<<edge_blocks, 256, 0, stream>>>(
        ea_bf, rsmu, src_s, dst_s, h_bf,
        bgh + (size_t)l * 65536, bm2 + (size_t)l * 16384,
        w2e + (size_t)l * 8192, msg_b2 + l * H, agg);
    k_node_up2<<<nup_blocks, 256, 0, stream>>>(
        agg, h_bf, h,
        brs1 + (size_t)l * 32768, brs2 + (size_t)l * 16384,
        res_b1 + l * H, res_b2 + l * H,
        ln_g + l * H, ln_b + l * H, h, h_bf);
  }

  hipMemsetAsync(gsum, 0, ((size_t)NG * H + NG) * 4, stream);
  k_pool<<<(NN + 31) / 32, 256, 0, stream>>>(h, batch, gsum, gcnt);
  k_readout<<<NG, 128, 0, stream>>>(gsum, gcnt, ro_w1, ro_b1, ro_w2, ro_b2, (float*)d_out);
}